// Round 1
// baseline (2952.338 us; speedup 1.0000x reference)
//
#include <hip/hip_runtime.h>

// NGCF forward on gfx950 — round 7: kill scatter_edges' 8x write amplification
// (WRITE_SIZE 298 MB vs 38.4 MB ideal, 251 us) with a two-level bucketed
// scatter. Rows are grouped 64-per-bucket; bucket base offsets come free from
// rowPtr. Phase A scatters packed (col|rlocal, val) records to per-bucket
// frontiers (L2-resident, amp~1); phase B (one WG per bucket) places each edge
// at its exact CSR slot inside a contiguous ~16 KB window (L2-resident, amp~1).
// Temp records reuse nbuf (spmm rewrites it every layer).

#define EMB 64

constexpr int kNUsers = 100000;
constexpr int kNItems = 50000;
constexpr int kNNodes = 150000;
constexpr int kNEdges = 4800000;
constexpr int kBatch  = 16384;
constexpr int kLayers = 3;
constexpr int kScanB  = (kNNodes + 255) / 256;   // 586 scan blocks
constexpr int kRPB    = 64;                      // rows per bucket
constexpr int kNBuckets = (kNNodes + kRPB - 1) / kRPB;  // 2344
constexpr int kEPW    = 16;                      // fallback only

__device__ __forceinline__ float f4c(const float4& v, int i) {
  return ((const float*)&v)[i];
}
__device__ __forceinline__ float4 f4fma(float s, float4 w, float4 a) {
  a.x = fmaf(s, w.x, a.x);
  a.y = fmaf(s, w.y, a.y);
  a.z = fmaf(s, w.z, a.z);
  a.w = fmaf(s, w.w, a.w);
  return a;
}
__device__ __forceinline__ float lrelu(float x) { return x > 0.f ? x : 0.2f * x; }
__device__ __forceinline__ unsigned short f2bf(float f) {   // RNE
  unsigned int u = __float_as_uint(f);
  u = (u + 0x7fffu + ((u >> 16) & 1u)) >> 16;
  return (unsigned short)u;
}
__device__ __forceinline__ float bf2f(unsigned short h) {
  return __uint_as_float(((unsigned int)h) << 16);
}

// ---------------------------------------------------------------------------
// init: cur = concat(user_emb, item_emb); cur16 = bf16(cur).
// ---------------------------------------------------------------------------
__global__ __launch_bounds__(256) void init_embed(
    const float* __restrict__ user_emb, const float* __restrict__ item_emb,
    float* __restrict__ cur, unsigned short* __restrict__ cur16, int with16)
{
  const size_t userF = (size_t)kNUsers * EMB;
  const size_t allF4 = (size_t)kNNodes * EMB / 4;
  const size_t i = (size_t)blockIdx.x * 256 + threadIdx.x;
  if (i >= allF4) return;
  const size_t f = i * 4;
  const float4 v = (f < userF) ? ((const float4*)user_emb)[i]
                               : ((const float4*)(item_emb))[(f - userF) / 4];
  ((float4*)cur)[i] = v;
  if (with16) {
    ushort4 h;
    h.x = f2bf(v.x); h.y = f2bf(v.y); h.z = f2bf(v.z); h.w = f2bf(v.w);
    ((ushort4*)cur16)[i] = h;
  }
}

// Streaming bf16 shadow refresh: cur16 = bf16(cur).
__global__ __launch_bounds__(256) void refresh16(
    const float* __restrict__ cur, unsigned short* __restrict__ cur16)
{
  const size_t allF4 = (size_t)kNNodes * EMB / 4;
  const size_t i = (size_t)blockIdx.x * 256 + threadIdx.x;
  if (i >= allF4) return;
  const float4 v = ((const float4*)cur)[i];
  ushort4 h;
  h.x = f2bf(v.x); h.y = f2bf(v.y); h.z = f2bf(v.z); h.w = f2bf(v.w);
  ((ushort4*)cur16)[i] = h;
}

// ---------------------------------------------------------------------------
// CSR build
// ---------------------------------------------------------------------------
__global__ __launch_bounds__(256) void hist_rows(
    const int* __restrict__ rows, int* __restrict__ rowCnt)
{
  const int e = blockIdx.x * 256 + threadIdx.x;
  if (e < kNEdges) atomicAdd(&rowCnt[rows[e]], 1);
}

__global__ __launch_bounds__(256) void scan1(
    int* __restrict__ rowCnt, int* __restrict__ rowPtr,
    int* __restrict__ blockSums)
{
  __shared__ int wsum[4];
  const int tid  = threadIdx.x;
  const int lane = tid & 63;
  const int wid  = tid >> 6;
  const int i    = blockIdx.x * 256 + tid;
  const int cnt  = (i < kNNodes) ? rowCnt[i] : 0;
  int v = cnt;
#pragma unroll
  for (int off = 1; off < 64; off <<= 1) {
    const int n = __shfl_up(v, off, 64);
    if (lane >= off) v += n;
  }
  if (lane == 63) wsum[wid] = v;
  __syncthreads();
  if (tid == 0) {
    int s = 0;
#pragma unroll
    for (int w = 0; w < 4; ++w) { const int t = wsum[w]; wsum[w] = s; s += t; }
    blockSums[blockIdx.x] = s;
  }
  __syncthreads();
  if (i < kNNodes) {
    rowPtr[i] = wsum[wid] + v - cnt;
    rowCnt[i] = 0;
  }
}

__global__ __launch_bounds__(1024) void scan2(int* __restrict__ blockSums)
{
  __shared__ int wsum[16];
  const int tid  = threadIdx.x;
  const int lane = tid & 63;
  const int wid  = tid >> 6;
  const int cnt  = (tid < kScanB) ? blockSums[tid] : 0;
  int v = cnt;
#pragma unroll
  for (int off = 1; off < 64; off <<= 1) {
    const int n = __shfl_up(v, off, 64);
    if (lane >= off) v += n;
  }
  if (lane == 63) wsum[wid] = v;
  __syncthreads();
  if (tid == 0) {
    int s = 0;
#pragma unroll
    for (int w = 0; w < 16; ++w) { const int t = wsum[w]; wsum[w] = s; s += t; }
  }
  __syncthreads();
  if (tid < kScanB) blockSums[tid] = wsum[wid] + v - cnt;
}

__global__ __launch_bounds__(256) void scan3(
    int* __restrict__ rowPtr, const int* __restrict__ blockSums,
    int* __restrict__ bucketBase)
{
  const int i = blockIdx.x * 256 + threadIdx.x;
  if (i < kNNodes) {
    const int v = rowPtr[i] + blockSums[blockIdx.x];
    rowPtr[i] = v;
    if ((i & (kRPB - 1)) == 0) bucketBase[i / kRPB] = v;
  }
  if (i == 0) {
    rowPtr[kNNodes] = kNEdges;
    bucketBase[kNBuckets] = kNEdges;
  }
}

// Phase A: scatter packed edge records to per-bucket frontiers.
// Record: x = col | (rlocal << 18)   (col < 2^18, rlocal < 64), y = val bits.
// Frontier lines (2344 x 64 B ~ 150 KB) stay L2-resident -> write amp ~ 1.
__global__ __launch_bounds__(256) void bucket_scatter(
    const int* __restrict__ rows, const int* __restrict__ cols,
    const float* __restrict__ vals, const int* __restrict__ bucketBase,
    int* __restrict__ bucketCnt, int2* __restrict__ tmpE)
{
  const int e = blockIdx.x * 256 + threadIdx.x;
  if (e >= kNEdges) return;
  const int r = rows[e];
  const int b = r / kRPB;
  const int idx = bucketBase[b] + atomicAdd(&bucketCnt[b], 1);
  tmpE[idx] = make_int2(cols[e] | ((r & (kRPB - 1)) << 18),
                        __float_as_int(vals[e]));
}

// Phase B: one WG per bucket; place each record at its exact CSR slot.
// Source slab and destination window are both contiguous (~16 KB each).
__global__ __launch_bounds__(256) void bucket_to_csr(
    const int2* __restrict__ tmpE, const int* __restrict__ rowPtr,
    const int* __restrict__ bucketBase, int* __restrict__ rowCnt,
    int2* __restrict__ edgeS)
{
  const int b     = blockIdx.x;
  const int r0    = b * kRPB;
  const int start = bucketBase[b];
  const int end   = bucketBase[b + 1];
  for (int e = start + threadIdx.x; e < end; e += 256) {
    const int2 cv = tmpE[e];
    const int r   = r0 + ((cv.x >> 18) & (kRPB - 1));
    const int pos = rowPtr[r] + atomicAdd(&rowCnt[r], 1);
    edgeS[pos] = make_int2(cv.x & 0x3FFFF, cv.y);
  }
}

// ---------------------------------------------------------------------------
// CSR SpMM, bf16 gather: one wave per row, lane = dim; 128 B/edge gather.
// ---------------------------------------------------------------------------
__global__ __launch_bounds__(256) void spmm_csr16(
    const unsigned short* __restrict__ cur16, const int* __restrict__ rowPtr,
    const int2* __restrict__ edgeS, float* __restrict__ nbuf)
{
  const int lane = threadIdx.x & 63;
  const int r = (blockIdx.x << 2) | (threadIdx.x >> 6);
  if (r >= kNNodes) return;
  const int start = __builtin_amdgcn_readfirstlane(rowPtr[r]);
  const int end   = __builtin_amdgcn_readfirstlane(rowPtr[r + 1]);
  float a0 = 0.f, a1 = 0.f, a2 = 0.f, a3 = 0.f;
  int e = start;
  for (; e + 4 <= end; e += 4) {
    const int2 cv0 = edgeS[e];
    const int2 cv1 = edgeS[e + 1];
    const int2 cv2 = edgeS[e + 2];
    const int2 cv3 = edgeS[e + 3];
    const unsigned short u0 = cur16[(size_t)cv0.x * EMB + lane];
    const unsigned short u1 = cur16[(size_t)cv1.x * EMB + lane];
    const unsigned short u2 = cur16[(size_t)cv2.x * EMB + lane];
    const unsigned short u3 = cur16[(size_t)cv3.x * EMB + lane];
    a0 = fmaf(__int_as_float(cv0.y), bf2f(u0), a0);
    a1 = fmaf(__int_as_float(cv1.y), bf2f(u1), a1);
    a2 = fmaf(__int_as_float(cv2.y), bf2f(u2), a2);
    a3 = fmaf(__int_as_float(cv3.y), bf2f(u3), a3);
  }
  for (; e < end; ++e) {
    const int2 cv = edgeS[e];
    a0 = fmaf(__int_as_float(cv.y), bf2f(cur16[(size_t)cv.x * EMB + lane]), a0);
  }
  nbuf[(size_t)r * EMB + lane] = (a0 + a1) + (a2 + a3);
}

// fp32-gather variant (fallback when ws can't hold cur16)
__global__ __launch_bounds__(256) void spmm_csr(
    const float* __restrict__ cur, const int* __restrict__ rowPtr,
    const int2* __restrict__ edgeS, float* __restrict__ nbuf)
{
  const int lane = threadIdx.x & 63;
  const int r = (blockIdx.x << 2) | (threadIdx.x >> 6);
  if (r >= kNNodes) return;
  const int start = __builtin_amdgcn_readfirstlane(rowPtr[r]);
  const int end   = __builtin_amdgcn_readfirstlane(rowPtr[r + 1]);
  float a0 = 0.f, a1 = 0.f, a2 = 0.f, a3 = 0.f;
  int e = start;
  for (; e + 4 <= end; e += 4) {
    const int2 cv0 = edgeS[e];
    const int2 cv1 = edgeS[e + 1];
    const int2 cv2 = edgeS[e + 2];
    const int2 cv3 = edgeS[e + 3];
    a0 = fmaf(__int_as_float(cv0.y), cur[(size_t)cv0.x * EMB + lane], a0);
    a1 = fmaf(__int_as_float(cv1.y), cur[(size_t)cv1.x * EMB + lane], a1);
    a2 = fmaf(__int_as_float(cv2.y), cur[(size_t)cv2.x * EMB + lane], a2);
    a3 = fmaf(__int_as_float(cv3.y), cur[(size_t)cv3.x * EMB + lane], a3);
  }
  for (; e < end; ++e) {
    const int2 cv = edgeS[e];
    a0 = fmaf(__int_as_float(cv.y), cur[(size_t)cv.x * EMB + lane], a0);
  }
  nbuf[(size_t)r * EMB + lane] = (a0 + a1) + (a2 + a3);
}

__global__ __launch_bounds__(256) void spmm_atomic(
    const float* __restrict__ cur, const int* __restrict__ rows,
    const int* __restrict__ cols, const float* __restrict__ vals,
    float* __restrict__ nbuf)
{
  const int lane = threadIdx.x & 63;
  int wv = (blockIdx.x << 2) | (threadIdx.x >> 6);
  wv = __builtin_amdgcn_readfirstlane(wv);
  int e0 = wv * kEPW;
  int e1 = e0 + kEPW;
  if (e1 > kNEdges) e1 = kNEdges;
  for (int e = e0; e < e1; ++e) {
    atomicAdd(nbuf + (size_t)rows[e] * EMB + lane,
              vals[e] * cur[(size_t)cols[e] * EMB + lane]);
  }
}

// ---------------------------------------------------------------------------
// Fused per-node transform — unchanged.
// ---------------------------------------------------------------------------
__global__ __launch_bounds__(256) void transform_inplace(
    float* __restrict__ cur, const float* __restrict__ nbuf,
    const float* __restrict__ W1, const float* __restrict__ b1,
    const float* __restrict__ W2, const float* __restrict__ b2)
{
  const int node = blockIdx.x * 256 + threadIdx.x;
  if (node >= kNNodes) return;

  const float4* __restrict__ xr  = (const float4*)(cur  + (size_t)node * EMB);
  const float4* __restrict__ nr  = (const float4*)(nbuf + (size_t)node * EMB);
  const float4* __restrict__ b1v = (const float4*)b1;
  const float4* __restrict__ b2v = (const float4*)b2;

  float4 acc1[16], acc2[16];
#pragma unroll
  for (int j = 0; j < 16; ++j) { acc1[j] = b1v[j]; acc2[j] = b2v[j]; }

#pragma unroll 2
  for (int k4 = 0; k4 < 16; ++k4) {
    const float4 xv = xr[k4];
    const float4 nv = nr[k4];
#pragma unroll
    for (int kk = 0; kk < 4; ++kk) {
      const int k = 4 * k4 + kk;
      const float xs = f4c(xv, kk);
      const float ns = f4c(nv, kk);
      const float4* __restrict__ w1r = (const float4*)(W1 + k * EMB);
      const float4* __restrict__ w2r = (const float4*)(W2 + k * EMB);
#pragma unroll
      for (int j = 0; j < 16; ++j) {
        acc1[j] = f4fma(xs, w1r[j], acc1[j]);
        acc2[j] = f4fma(ns, w2r[j], acc2[j]);
      }
    }
  }

#pragma unroll
  for (int k4 = 0; k4 < 16; ++k4) {
    const float4 xv = xr[k4];
    const float4 tv = acc2[k4];
#pragma unroll
    for (int kk = 0; kk < 4; ++kk) {
      const float ms = f4c(tv, kk) * f4c(xv, kk);
      const float4* __restrict__ w2r = (const float4*)(W2 + (4 * k4 + kk) * EMB);
#pragma unroll
      for (int j = 0; j < 16; ++j) acc1[j] = f4fma(ms, w2r[j], acc1[j]);
    }
  }

  float4* __restrict__ outp = (float4*)(cur + (size_t)node * EMB);
#pragma unroll
  for (int j = 0; j < 16; ++j) {
    float4 r;
    r.x = lrelu(acc1[j].x + acc2[j].x + b2v[j].x);
    r.y = lrelu(acc1[j].y + acc2[j].y + b2v[j].y);
    r.z = lrelu(acc1[j].z + acc2[j].z + b2v[j].z);
    r.w = lrelu(acc1[j].w + acc2[j].w + b2v[j].w);
    outp[j] = r;
  }
}

// ---------------------------------------------------------------------------
__global__ __launch_bounds__(256) void gather_out(
    const float* __restrict__ cur, const int* __restrict__ users,
    const int* __restrict__ pos, const int* __restrict__ neg,
    float* __restrict__ out, int layer)
{
  const int t    = blockIdx.x * 256 + threadIdx.x;
  const int lane = t & 63;
  const int rid  = t >> 6;
  if (rid >= 3 * kBatch) return;
  const int seg = rid / kBatch;
  const int b   = rid - seg * kBatch;
  int idx;
  if (seg == 0)      idx = users[b];
  else if (seg == 1) idx = pos[b] + kNUsers;
  else               idx = neg[b] + kNUsers;
  out[(size_t)rid * 256 + layer * EMB + lane] = cur[(size_t)idx * EMB + lane];
}

// ---------------------------------------------------------------------------
extern "C" void kernel_launch(void* const* d_in, const int* in_sizes, int n_in,
                              void* d_out, int out_size, void* d_ws, size_t ws_size,
                              hipStream_t stream) {
  const int*   users    = (const int*)d_in[0];
  const int*   pos      = (const int*)d_in[1];
  const int*   neg      = (const int*)d_in[2];
  const int*   rows     = (const int*)d_in[3];
  const int*   cols     = (const int*)d_in[4];
  const float* vals     = (const float*)d_in[5];
  const float* user_emb = (const float*)d_in[6];
  const float* item_emb = (const float*)d_in[7];
  const float* W1s      = (const float*)d_in[8];
  const float* b1s      = (const float*)d_in[9];
  const float* W2s      = (const float*)d_in[10];
  const float* b2s      = (const float*)d_in[11];
  float* out = (float*)d_out;

  const size_t nodeF = (size_t)kNNodes * EMB;
  float* cur  = (float*)d_ws;                               // 38.4 MB
  float* nbuf = cur + nodeF;                                // 38.4 MB (tmpE alias)
  int2*  edgeS      = (int2*)(nbuf + nodeF);                // 38.4 MB
  int*   rowPtr     = (int*)(edgeS + kNEdges);              // 600 KB (+1)
  int*   rowCnt     = rowPtr + (kNNodes + 1);               // 600 KB
  int*   blockSums  = rowCnt + kNNodes;                     // 2.3 KB
  int*   bucketCnt  = blockSums + kScanB;                   // 9.4 KB
  int*   bucketBase = bucketCnt + kNBuckets;                // 9.4 KB (+1)
  unsigned short* cur16 = (unsigned short*)(bucketBase + (kNBuckets + 1)); // 19.2 MB
  int2*  tmpE = (int2*)nbuf;                                // phase-A records
  const size_t neededCsr = (size_t)((char*)cur16 - (char*)d_ws);
  const size_t needed16  = neededCsr + nodeF * sizeof(unsigned short);
  const bool useCsr = ws_size >= neededCsr;
  const bool use16  = useCsr && ws_size >= needed16;

  const dim3 blk(256);
  const int iblocks = (int)((nodeF / 4 + 255) / 256);       // 9375
  const int gblocks = (3 * kBatch * EMB + 255) / 256;       // 12288
  const int eblocks = (kNEdges + 255) / 256;                // 18750
  const int rblocks = (kNNodes + 3) / 4;                    // 37500
  const int tblocks = (kNNodes + 255) / 256;                // 586

  init_embed<<<iblocks, blk, 0, stream>>>(user_emb, item_emb, cur, cur16,
                                          use16 ? 1 : 0);

  if (useCsr) {
    // one memset covers rowCnt + blockSums + bucketCnt (contiguous)
    hipMemsetAsync(rowCnt, 0,
                   (size_t)(kNNodes + kScanB + kNBuckets) * sizeof(int), stream);
    hist_rows<<<eblocks, blk, 0, stream>>>(rows, rowCnt);
    scan1<<<kScanB, blk, 0, stream>>>(rowCnt, rowPtr, blockSums);
    scan2<<<1, 1024, 0, stream>>>(blockSums);
    scan3<<<kScanB, blk, 0, stream>>>(rowPtr, blockSums, bucketBase);
    bucket_scatter<<<eblocks, blk, 0, stream>>>(rows, cols, vals, bucketBase,
                                                bucketCnt, tmpE);
    bucket_to_csr<<<kNBuckets, blk, 0, stream>>>(tmpE, rowPtr, bucketBase,
                                                 rowCnt, edgeS);
  }

  gather_out<<<gblocks, blk, 0, stream>>>(cur, users, pos, neg, out, 0);

  for (int L = 0; L < kLayers; ++L) {
    if (useCsr) {
      if (use16)
        spmm_csr16<<<rblocks, blk, 0, stream>>>(cur16, rowPtr, edgeS, nbuf);
      else
        spmm_csr<<<rblocks, blk, 0, stream>>>(cur, rowPtr, edgeS, nbuf);
    } else {
      hipMemsetAsync(nbuf, 0, nodeF * sizeof(float), stream);
      const int sblocks = (((kNEdges + kEPW - 1) / kEPW) + 3) / 4;
      spmm_atomic<<<sblocks, blk, 0, stream>>>(cur, rows, cols, vals, nbuf);
    }
    transform_inplace<<<tblocks, blk, 0, stream>>>(
        cur, nbuf, W1s + L * EMB * EMB, b1s + L * EMB,
        W2s + L * EMB * EMB, b2s + L * EMB);
    if (use16 && L + 1 < kLayers)
      refresh16<<<iblocks, blk, 0, stream>>>(cur, cur16);
    gather_out<<<gblocks, blk, 0, stream>>>(cur, users, pos, neg, out, L + 1);
  }
}

// Round 2
// 1651.890 us; speedup vs baseline: 1.7872x; 1.7872x over previous
//
#include <hip/hip_runtime.h>

// NGCF forward on gfx950 — round 8: revert the bucketed scatter (2344 hot
// atomic addresses = 1500 us of serialization, R7 post-mortem) and instead
// kill scatter write-amplification with XCD-sliced destinations: block b
// (dispatched round-robin to XCD b%8) handles only edges whose row is in
// slice b&7 (4.8 MB destination window ~= one XCD's 4 MB L2). Each edgeS
// line is written by exactly ONE XCD -> no cross-XCD line bouncing; per-row
// rank atomics (150K addresses, ~32 RMW each) become XCD-local too. The 8x
// re-read of the 57.6 MB edge stream is absorbed by the 256 MB L3.

#define EMB 64

constexpr int kNUsers = 100000;
constexpr int kNItems = 50000;
constexpr int kNNodes = 150000;
constexpr int kNEdges = 4800000;
constexpr int kBatch  = 16384;
constexpr int kLayers = 3;
constexpr int kScanB  = (kNNodes + 255) / 256;   // 586 scan blocks
constexpr int kSlices = 8;                       // = XCD count
constexpr int kRowsPerSlice = kNNodes / kSlices; // 18750
constexpr int kCPS    = 2048;                    // chunks per slice
constexpr int kEPC    = (kNEdges + kCPS - 1) / kCPS; // 2344 edges per chunk
constexpr int kEPW    = 16;                      // fallback only

__device__ __forceinline__ float f4c(const float4& v, int i) {
  return ((const float*)&v)[i];
}
__device__ __forceinline__ float4 f4fma(float s, float4 w, float4 a) {
  a.x = fmaf(s, w.x, a.x);
  a.y = fmaf(s, w.y, a.y);
  a.z = fmaf(s, w.z, a.z);
  a.w = fmaf(s, w.w, a.w);
  return a;
}
__device__ __forceinline__ float lrelu(float x) { return x > 0.f ? x : 0.2f * x; }
__device__ __forceinline__ unsigned short f2bf(float f) {   // RNE
  unsigned int u = __float_as_uint(f);
  u = (u + 0x7fffu + ((u >> 16) & 1u)) >> 16;
  return (unsigned short)u;
}
__device__ __forceinline__ float bf2f(unsigned short h) {
  return __uint_as_float(((unsigned int)h) << 16);
}

// ---------------------------------------------------------------------------
// init: cur = concat(user_emb, item_emb); cur16 = bf16(cur).
// ---------------------------------------------------------------------------
__global__ __launch_bounds__(256) void init_embed(
    const float* __restrict__ user_emb, const float* __restrict__ item_emb,
    float* __restrict__ cur, unsigned short* __restrict__ cur16, int with16)
{
  const size_t userF = (size_t)kNUsers * EMB;
  const size_t allF4 = (size_t)kNNodes * EMB / 4;
  const size_t i = (size_t)blockIdx.x * 256 + threadIdx.x;
  if (i >= allF4) return;
  const size_t f = i * 4;
  const float4 v = (f < userF) ? ((const float4*)user_emb)[i]
                               : ((const float4*)(item_emb))[(f - userF) / 4];
  ((float4*)cur)[i] = v;
  if (with16) {
    ushort4 h;
    h.x = f2bf(v.x); h.y = f2bf(v.y); h.z = f2bf(v.z); h.w = f2bf(v.w);
    ((ushort4*)cur16)[i] = h;
  }
}

// Streaming bf16 shadow refresh: cur16 = bf16(cur).
__global__ __launch_bounds__(256) void refresh16(
    const float* __restrict__ cur, unsigned short* __restrict__ cur16)
{
  const size_t allF4 = (size_t)kNNodes * EMB / 4;
  const size_t i = (size_t)blockIdx.x * 256 + threadIdx.x;
  if (i >= allF4) return;
  const float4 v = ((const float4*)cur)[i];
  ushort4 h;
  h.x = f2bf(v.x); h.y = f2bf(v.y); h.z = f2bf(v.z); h.w = f2bf(v.w);
  ((ushort4*)cur16)[i] = h;
}

// ---------------------------------------------------------------------------
// CSR build
// ---------------------------------------------------------------------------
__global__ __launch_bounds__(256) void hist_rows(
    const int* __restrict__ rows, int* __restrict__ rowCnt)
{
  const int e = blockIdx.x * 256 + threadIdx.x;
  if (e < kNEdges) atomicAdd(&rowCnt[rows[e]], 1);
}

__global__ __launch_bounds__(256) void scan1(
    int* __restrict__ rowCnt, int* __restrict__ rowPtr,
    int* __restrict__ blockSums)
{
  __shared__ int wsum[4];
  const int tid  = threadIdx.x;
  const int lane = tid & 63;
  const int wid  = tid >> 6;
  const int i    = blockIdx.x * 256 + tid;
  const int cnt  = (i < kNNodes) ? rowCnt[i] : 0;
  int v = cnt;
#pragma unroll
  for (int off = 1; off < 64; off <<= 1) {
    const int n = __shfl_up(v, off, 64);
    if (lane >= off) v += n;
  }
  if (lane == 63) wsum[wid] = v;
  __syncthreads();
  if (tid == 0) {
    int s = 0;
#pragma unroll
    for (int w = 0; w < 4; ++w) { const int t = wsum[w]; wsum[w] = s; s += t; }
    blockSums[blockIdx.x] = s;
  }
  __syncthreads();
  if (i < kNNodes) {
    rowPtr[i] = wsum[wid] + v - cnt;
    rowCnt[i] = 0;
  }
}

__global__ __launch_bounds__(1024) void scan2(int* __restrict__ blockSums)
{
  __shared__ int wsum[16];
  const int tid  = threadIdx.x;
  const int lane = tid & 63;
  const int wid  = tid >> 6;
  const int cnt  = (tid < kScanB) ? blockSums[tid] : 0;
  int v = cnt;
#pragma unroll
  for (int off = 1; off < 64; off <<= 1) {
    const int n = __shfl_up(v, off, 64);
    if (lane >= off) v += n;
  }
  if (lane == 63) wsum[wid] = v;
  __syncthreads();
  if (tid == 0) {
    int s = 0;
#pragma unroll
    for (int w = 0; w < 16; ++w) { const int t = wsum[w]; wsum[w] = s; s += t; }
  }
  __syncthreads();
  if (tid < kScanB) blockSums[tid] = wsum[wid] + v - cnt;
}

__global__ __launch_bounds__(256) void scan3(
    int* __restrict__ rowPtr, const int* __restrict__ blockSums)
{
  const int i = blockIdx.x * 256 + threadIdx.x;
  if (i < kNNodes) rowPtr[i] += blockSums[blockIdx.x];
  if (i == 0) rowPtr[kNNodes] = kNEdges;
}

// XCD-sliced scatter: block b -> XCD b%8 (round-robin dispatch heuristic);
// it handles only edges whose row lies in slice b&7. Destination window per
// slice = 4.8 MB ~= one XCD's L2, so each edgeS line is write-allocated and
// evicted exactly once by exactly one XCD. rows[] re-reads hit L3.
__global__ __launch_bounds__(256) void scatter_xcd(
    const int* __restrict__ rows, const int* __restrict__ cols,
    const float* __restrict__ vals, const int* __restrict__ rowPtr,
    int* __restrict__ rowCnt, int2* __restrict__ edgeS)
{
  const int slice = blockIdx.x & (kSlices - 1);
  const int chunk = blockIdx.x >> 3;
  const int lo = slice * kRowsPerSlice;
  const int hi = lo + kRowsPerSlice;
  const int e0 = chunk * kEPC;
  int e1 = e0 + kEPC;
  if (e1 > kNEdges) e1 = kNEdges;
  for (int e = e0 + threadIdx.x; e < e1; e += 256) {
    const int r = rows[e];
    if (r >= lo && r < hi) {
      const int idx = rowPtr[r] + atomicAdd(&rowCnt[r], 1);
      edgeS[idx] = make_int2(cols[e], __float_as_int(vals[e]));
    }
  }
}

// ---------------------------------------------------------------------------
// CSR SpMM, bf16 gather: one wave per row, lane = dim; 128 B/edge gather.
// ---------------------------------------------------------------------------
__global__ __launch_bounds__(256) void spmm_csr16(
    const unsigned short* __restrict__ cur16, const int* __restrict__ rowPtr,
    const int2* __restrict__ edgeS, float* __restrict__ nbuf)
{
  const int lane = threadIdx.x & 63;
  const int r = (blockIdx.x << 2) | (threadIdx.x >> 6);
  if (r >= kNNodes) return;
  const int start = __builtin_amdgcn_readfirstlane(rowPtr[r]);
  const int end   = __builtin_amdgcn_readfirstlane(rowPtr[r + 1]);
  float a0 = 0.f, a1 = 0.f, a2 = 0.f, a3 = 0.f;
  int e = start;
  for (; e + 4 <= end; e += 4) {
    const int2 cv0 = edgeS[e];
    const int2 cv1 = edgeS[e + 1];
    const int2 cv2 = edgeS[e + 2];
    const int2 cv3 = edgeS[e + 3];
    const unsigned short u0 = cur16[(size_t)cv0.x * EMB + lane];
    const unsigned short u1 = cur16[(size_t)cv1.x * EMB + lane];
    const unsigned short u2 = cur16[(size_t)cv2.x * EMB + lane];
    const unsigned short u3 = cur16[(size_t)cv3.x * EMB + lane];
    a0 = fmaf(__int_as_float(cv0.y), bf2f(u0), a0);
    a1 = fmaf(__int_as_float(cv1.y), bf2f(u1), a1);
    a2 = fmaf(__int_as_float(cv2.y), bf2f(u2), a2);
    a3 = fmaf(__int_as_float(cv3.y), bf2f(u3), a3);
  }
  for (; e < end; ++e) {
    const int2 cv = edgeS[e];
    a0 = fmaf(__int_as_float(cv.y), bf2f(cur16[(size_t)cv.x * EMB + lane]), a0);
  }
  nbuf[(size_t)r * EMB + lane] = (a0 + a1) + (a2 + a3);
}

// fp32-gather variant (fallback when ws can't hold cur16)
__global__ __launch_bounds__(256) void spmm_csr(
    const float* __restrict__ cur, const int* __restrict__ rowPtr,
    const int2* __restrict__ edgeS, float* __restrict__ nbuf)
{
  const int lane = threadIdx.x & 63;
  const int r = (blockIdx.x << 2) | (threadIdx.x >> 6);
  if (r >= kNNodes) return;
  const int start = __builtin_amdgcn_readfirstlane(rowPtr[r]);
  const int end   = __builtin_amdgcn_readfirstlane(rowPtr[r + 1]);
  float a0 = 0.f, a1 = 0.f, a2 = 0.f, a3 = 0.f;
  int e = start;
  for (; e + 4 <= end; e += 4) {
    const int2 cv0 = edgeS[e];
    const int2 cv1 = edgeS[e + 1];
    const int2 cv2 = edgeS[e + 2];
    const int2 cv3 = edgeS[e + 3];
    a0 = fmaf(__int_as_float(cv0.y), cur[(size_t)cv0.x * EMB + lane], a0);
    a1 = fmaf(__int_as_float(cv1.y), cur[(size_t)cv1.x * EMB + lane], a1);
    a2 = fmaf(__int_as_float(cv2.y), cur[(size_t)cv2.x * EMB + lane], a2);
    a3 = fmaf(__int_as_float(cv3.y), cur[(size_t)cv3.x * EMB + lane], a3);
  }
  for (; e < end; ++e) {
    const int2 cv = edgeS[e];
    a0 = fmaf(__int_as_float(cv.y), cur[(size_t)cv.x * EMB + lane], a0);
  }
  nbuf[(size_t)r * EMB + lane] = (a0 + a1) + (a2 + a3);
}

__global__ __launch_bounds__(256) void spmm_atomic(
    const float* __restrict__ cur, const int* __restrict__ rows,
    const int* __restrict__ cols, const float* __restrict__ vals,
    float* __restrict__ nbuf)
{
  const int lane = threadIdx.x & 63;
  int wv = (blockIdx.x << 2) | (threadIdx.x >> 6);
  wv = __builtin_amdgcn_readfirstlane(wv);
  int e0 = wv * kEPW;
  int e1 = e0 + kEPW;
  if (e1 > kNEdges) e1 = kNEdges;
  for (int e = e0; e < e1; ++e) {
    atomicAdd(nbuf + (size_t)rows[e] * EMB + lane,
              vals[e] * cur[(size_t)cols[e] * EMB + lane]);
  }
}

// ---------------------------------------------------------------------------
// Fused per-node transform — unchanged.
// ---------------------------------------------------------------------------
__global__ __launch_bounds__(256) void transform_inplace(
    float* __restrict__ cur, const float* __restrict__ nbuf,
    const float* __restrict__ W1, const float* __restrict__ b1,
    const float* __restrict__ W2, const float* __restrict__ b2)
{
  const int node = blockIdx.x * 256 + threadIdx.x;
  if (node >= kNNodes) return;

  const float4* __restrict__ xr  = (const float4*)(cur  + (size_t)node * EMB);
  const float4* __restrict__ nr  = (const float4*)(nbuf + (size_t)node * EMB);
  const float4* __restrict__ b1v = (const float4*)b1;
  const float4* __restrict__ b2v = (const float4*)b2;

  float4 acc1[16], acc2[16];
#pragma unroll
  for (int j = 0; j < 16; ++j) { acc1[j] = b1v[j]; acc2[j] = b2v[j]; }

#pragma unroll 2
  for (int k4 = 0; k4 < 16; ++k4) {
    const float4 xv = xr[k4];
    const float4 nv = nr[k4];
#pragma unroll
    for (int kk = 0; kk < 4; ++kk) {
      const int k = 4 * k4 + kk;
      const float xs = f4c(xv, kk);
      const float ns = f4c(nv, kk);
      const float4* __restrict__ w1r = (const float4*)(W1 + k * EMB);
      const float4* __restrict__ w2r = (const float4*)(W2 + k * EMB);
#pragma unroll
      for (int j = 0; j < 16; ++j) {
        acc1[j] = f4fma(xs, w1r[j], acc1[j]);
        acc2[j] = f4fma(ns, w2r[j], acc2[j]);
      }
    }
  }

#pragma unroll
  for (int k4 = 0; k4 < 16; ++k4) {
    const float4 xv = xr[k4];
    const float4 tv = acc2[k4];
#pragma unroll
    for (int kk = 0; kk < 4; ++kk) {
      const float ms = f4c(tv, kk) * f4c(xv, kk);
      const float4* __restrict__ w2r = (const float4*)(W2 + (4 * k4 + kk) * EMB);
#pragma unroll
      for (int j = 0; j < 16; ++j) acc1[j] = f4fma(ms, w2r[j], acc1[j]);
    }
  }

  float4* __restrict__ outp = (float4*)(cur + (size_t)node * EMB);
#pragma unroll
  for (int j = 0; j < 16; ++j) {
    float4 r;
    r.x = lrelu(acc1[j].x + acc2[j].x + b2v[j].x);
    r.y = lrelu(acc1[j].y + acc2[j].y + b2v[j].y);
    r.z = lrelu(acc1[j].z + acc2[j].z + b2v[j].z);
    r.w = lrelu(acc1[j].w + acc2[j].w + b2v[j].w);
    outp[j] = r;
  }
}

// ---------------------------------------------------------------------------
__global__ __launch_bounds__(256) void gather_out(
    const float* __restrict__ cur, const int* __restrict__ users,
    const int* __restrict__ pos, const int* __restrict__ neg,
    float* __restrict__ out, int layer)
{
  const int t    = blockIdx.x * 256 + threadIdx.x;
  const int lane = t & 63;
  const int rid  = t >> 6;
  if (rid >= 3 * kBatch) return;
  const int seg = rid / kBatch;
  const int b   = rid - seg * kBatch;
  int idx;
  if (seg == 0)      idx = users[b];
  else if (seg == 1) idx = pos[b] + kNUsers;
  else               idx = neg[b] + kNUsers;
  out[(size_t)rid * 256 + layer * EMB + lane] = cur[(size_t)idx * EMB + lane];
}

// ---------------------------------------------------------------------------
extern "C" void kernel_launch(void* const* d_in, const int* in_sizes, int n_in,
                              void* d_out, int out_size, void* d_ws, size_t ws_size,
                              hipStream_t stream) {
  const int*   users    = (const int*)d_in[0];
  const int*   pos      = (const int*)d_in[1];
  const int*   neg      = (const int*)d_in[2];
  const int*   rows     = (const int*)d_in[3];
  const int*   cols     = (const int*)d_in[4];
  const float* vals     = (const float*)d_in[5];
  const float* user_emb = (const float*)d_in[6];
  const float* item_emb = (const float*)d_in[7];
  const float* W1s      = (const float*)d_in[8];
  const float* b1s      = (const float*)d_in[9];
  const float* W2s      = (const float*)d_in[10];
  const float* b2s      = (const float*)d_in[11];
  float* out = (float*)d_out;

  const size_t nodeF = (size_t)kNNodes * EMB;
  float* cur  = (float*)d_ws;                               // 38.4 MB
  float* nbuf = cur + nodeF;                                // 38.4 MB
  int2*  edgeS     = (int2*)(nbuf + nodeF);                 // 38.4 MB
  int*   rowPtr    = (int*)(edgeS + kNEdges);               // 600 KB (+1)
  int*   rowCnt    = rowPtr + (kNNodes + 1);                // 600 KB
  int*   blockSums = rowCnt + kNNodes;                      // 2.3 KB
  unsigned short* cur16 = (unsigned short*)(blockSums + kScanB);  // 19.2 MB
  const size_t neededCsr = (size_t)((char*)cur16 - (char*)d_ws);
  const size_t needed16  = neededCsr + nodeF * sizeof(unsigned short);
  const bool useCsr = ws_size >= neededCsr;
  const bool use16  = useCsr && ws_size >= needed16;

  const dim3 blk(256);
  const int iblocks = (int)((nodeF / 4 + 255) / 256);       // 9375
  const int gblocks = (3 * kBatch * EMB + 255) / 256;       // 12288
  const int eblocks = (kNEdges + 255) / 256;                // 18750
  const int rblocks = (kNNodes + 3) / 4;                    // 37500
  const int tblocks = (kNNodes + 255) / 256;                // 586
  const int sblocksX = kSlices * kCPS;                      // 16384

  init_embed<<<iblocks, blk, 0, stream>>>(user_emb, item_emb, cur, cur16,
                                          use16 ? 1 : 0);

  if (useCsr) {
    hipMemsetAsync(rowCnt, 0, (size_t)kNNodes * sizeof(int), stream);
    hist_rows<<<eblocks, blk, 0, stream>>>(rows, rowCnt);
    scan1<<<kScanB, blk, 0, stream>>>(rowCnt, rowPtr, blockSums);
    scan2<<<1, 1024, 0, stream>>>(blockSums);
    scan3<<<kScanB, blk, 0, stream>>>(rowPtr, blockSums);
    scatter_xcd<<<sblocksX, blk, 0, stream>>>(rows, cols, vals, rowPtr,
                                              rowCnt, edgeS);
  }

  gather_out<<<gblocks, blk, 0, stream>>>(cur, users, pos, neg, out, 0);

  for (int L = 0; L < kLayers; ++L) {
    if (useCsr) {
      if (use16)
        spmm_csr16<<<rblocks, blk, 0, stream>>>(cur16, rowPtr, edgeS, nbuf);
      else
        spmm_csr<<<rblocks, blk, 0, stream>>>(cur, rowPtr, edgeS, nbuf);
    } else {
      hipMemsetAsync(nbuf, 0, nodeF * sizeof(float), stream);
      const int sblocks = (((kNEdges + kEPW - 1) / kEPW) + 3) / 4;
      spmm_atomic<<<sblocks, blk, 0, stream>>>(cur, rows, cols, vals, nbuf);
    }
    transform_inplace<<<tblocks, blk, 0, stream>>>(
        cur, nbuf, W1s + L * EMB * EMB, b1s + L * EMB,
        W2s + L * EMB * EMB, b2s + L * EMB);
    if (use16 && L + 1 < kLayers)
      refresh16<<<iblocks, blk, 0, stream>>>(cur, cur16);
    gather_out<<<gblocks, blk, 0, stream>>>(cur, users, pos, neg, out, L + 1);
  }
}

// Round 3
// 1573.432 us; speedup vs baseline: 1.8764x; 1.0499x over previous
//
#include <hip/hip_runtime.h>

// NGCF forward on gfx950 — round 9: CSR build via hierarchical binning.
// R7/R8 post-mortem: scatter write-amp (~8x) comes from TEMPORAL sparsity —
// a row's 32 edges are spread across the whole stream, so each dest line is
// fetched+evicted ~8 times. Fix: (1) bin_edges groups edges into 586
// row-ranges (256 rows each) with per-block BULK-RESERVED contiguous bursts
// (one global atomic per block x range, burst-exclusive lines, amp~1.5);
// (2) place_edges: one WG per range, 64KB src + 64KB dst both L2-resident,
// LDS rank counters -> every edgeS line written exactly once (amp~1).

#define EMB 64

constexpr int kNUsers = 100000;
constexpr int kNItems = 50000;
constexpr int kNNodes = 150000;
constexpr int kNEdges = 4800000;
constexpr int kBatch  = 16384;
constexpr int kLayers = 3;
constexpr int kScanB  = (kNNodes + 255) / 256;   // 586 scan blocks
constexpr int kRngShift = 8;                     // 256 rows per range
constexpr int kNRanges  = (kNNodes + 255) >> 8;  // 586
constexpr int kEdgesPerBin = 16384;              // edges per bin block
constexpr int kBinBlocks = (kNEdges + kEdgesPerBin - 1) / kEdgesPerBin; // 293
constexpr int kEPW    = 16;                      // fallback only

__device__ __forceinline__ float f4c(const float4& v, int i) {
  return ((const float*)&v)[i];
}
__device__ __forceinline__ float4 f4fma(float s, float4 w, float4 a) {
  a.x = fmaf(s, w.x, a.x);
  a.y = fmaf(s, w.y, a.y);
  a.z = fmaf(s, w.z, a.z);
  a.w = fmaf(s, w.w, a.w);
  return a;
}
__device__ __forceinline__ float lrelu(float x) { return x > 0.f ? x : 0.2f * x; }
__device__ __forceinline__ unsigned short f2bf(float f) {   // RNE
  unsigned int u = __float_as_uint(f);
  u = (u + 0x7fffu + ((u >> 16) & 1u)) >> 16;
  return (unsigned short)u;
}
__device__ __forceinline__ float bf2f(unsigned short h) {
  return __uint_as_float(((unsigned int)h) << 16);
}

// ---------------------------------------------------------------------------
// init: cur = concat(user_emb, item_emb); cur16 = bf16(cur).
// ---------------------------------------------------------------------------
__global__ __launch_bounds__(256) void init_embed(
    const float* __restrict__ user_emb, const float* __restrict__ item_emb,
    float* __restrict__ cur, unsigned short* __restrict__ cur16, int with16)
{
  const size_t userF = (size_t)kNUsers * EMB;
  const size_t allF4 = (size_t)kNNodes * EMB / 4;
  const size_t i = (size_t)blockIdx.x * 256 + threadIdx.x;
  if (i >= allF4) return;
  const size_t f = i * 4;
  const float4 v = (f < userF) ? ((const float4*)user_emb)[i]
                               : ((const float4*)(item_emb))[(f - userF) / 4];
  ((float4*)cur)[i] = v;
  if (with16) {
    ushort4 h;
    h.x = f2bf(v.x); h.y = f2bf(v.y); h.z = f2bf(v.z); h.w = f2bf(v.w);
    ((ushort4*)cur16)[i] = h;
  }
}

// Streaming bf16 shadow refresh: cur16 = bf16(cur).
__global__ __launch_bounds__(256) void refresh16(
    const float* __restrict__ cur, unsigned short* __restrict__ cur16)
{
  const size_t allF4 = (size_t)kNNodes * EMB / 4;
  const size_t i = (size_t)blockIdx.x * 256 + threadIdx.x;
  if (i >= allF4) return;
  const float4 v = ((const float4*)cur)[i];
  ushort4 h;
  h.x = f2bf(v.x); h.y = f2bf(v.y); h.z = f2bf(v.z); h.w = f2bf(v.w);
  ((ushort4*)cur16)[i] = h;
}

// ---------------------------------------------------------------------------
// CSR build
// ---------------------------------------------------------------------------
__global__ __launch_bounds__(256) void hist_rows(
    const int* __restrict__ rows, int* __restrict__ rowCnt)
{
  const int e = blockIdx.x * 256 + threadIdx.x;
  if (e < kNEdges) atomicAdd(&rowCnt[rows[e]], 1);
}

__global__ __launch_bounds__(256) void scan1(
    int* __restrict__ rowCnt, int* __restrict__ rowPtr,
    int* __restrict__ blockSums)
{
  __shared__ int wsum[4];
  const int tid  = threadIdx.x;
  const int lane = tid & 63;
  const int wid  = tid >> 6;
  const int i    = blockIdx.x * 256 + tid;
  const int cnt  = (i < kNNodes) ? rowCnt[i] : 0;
  int v = cnt;
#pragma unroll
  for (int off = 1; off < 64; off <<= 1) {
    const int n = __shfl_up(v, off, 64);
    if (lane >= off) v += n;
  }
  if (lane == 63) wsum[wid] = v;
  __syncthreads();
  if (tid == 0) {
    int s = 0;
#pragma unroll
    for (int w = 0; w < 4; ++w) { const int t = wsum[w]; wsum[w] = s; s += t; }
    blockSums[blockIdx.x] = s;
  }
  __syncthreads();
  if (i < kNNodes) {
    rowPtr[i] = wsum[wid] + v - cnt;
    rowCnt[i] = 0;
  }
}

__global__ __launch_bounds__(1024) void scan2(int* __restrict__ blockSums)
{
  __shared__ int wsum[16];
  const int tid  = threadIdx.x;
  const int lane = tid & 63;
  const int wid  = tid >> 6;
  const int cnt  = (tid < kScanB) ? blockSums[tid] : 0;
  int v = cnt;
#pragma unroll
  for (int off = 1; off < 64; off <<= 1) {
    const int n = __shfl_up(v, off, 64);
    if (lane >= off) v += n;
  }
  if (lane == 63) wsum[wid] = v;
  __syncthreads();
  if (tid == 0) {
    int s = 0;
#pragma unroll
    for (int w = 0; w < 16; ++w) { const int t = wsum[w]; wsum[w] = s; s += t; }
  }
  __syncthreads();
  if (tid < kScanB) blockSums[tid] = wsum[wid] + v - cnt;
}

__global__ __launch_bounds__(256) void scan3(
    int* __restrict__ rowPtr, const int* __restrict__ blockSums)
{
  const int i = blockIdx.x * 256 + threadIdx.x;
  if (i < kNNodes) rowPtr[i] += blockSums[blockIdx.x];
  if (i == 0) rowPtr[kNNodes] = kNEdges;
}

// Pass 1: bin edges into 586 row-ranges. Per block: LDS histogram, ONE
// global atomic per (block,range) reserving a contiguous burst, then scatter
// into the exclusively-owned burst. Record: col | localRow<<18.
__global__ __launch_bounds__(256) void bin_edges(
    const int* __restrict__ rows, const int* __restrict__ cols,
    const float* __restrict__ vals, const int* __restrict__ rowPtr,
    int* __restrict__ rangeCnt, int2* __restrict__ tmpE)
{
  __shared__ int cnt[kNRanges];
  __shared__ int base[kNRanges];
  const int tid = threadIdx.x;
  const int e0  = blockIdx.x * kEdgesPerBin;
  int e1 = e0 + kEdgesPerBin;
  if (e1 > kNEdges) e1 = kNEdges;

  for (int b = tid; b < kNRanges; b += 256) cnt[b] = 0;
  __syncthreads();
  for (int e = e0 + tid; e < e1; e += 256)
    atomicAdd(&cnt[rows[e] >> kRngShift], 1);
  __syncthreads();
  for (int b = tid; b < kNRanges; b += 256) {
    const int c = cnt[b];
    base[b] = (c > 0) ? (rowPtr[b << kRngShift] + atomicAdd(&rangeCnt[b], c))
                      : 0;
    cnt[b] = 0;
  }
  __syncthreads();
  for (int e = e0 + tid; e < e1; e += 256) {
    const int r = rows[e];
    const int b = r >> kRngShift;
    const int rank = atomicAdd(&cnt[b], 1);
    tmpE[base[b] + rank] =
        make_int2(cols[e] | ((r & 255) << 18), __float_as_int(vals[e]));
  }
}

// Pass 2: one WG per range. Src slab (contiguous, ~64KB) and dst CSR window
// (contiguous, ~64KB) are both L2-resident; LDS rank counters give exact
// CSR slots. Every edgeS line is written exactly once.
__global__ __launch_bounds__(256) void place_edges(
    const int2* __restrict__ tmpE, const int* __restrict__ rowPtr,
    int2* __restrict__ edgeS)
{
  __shared__ int lcnt[256];
  const int b   = blockIdx.x;
  const int r0  = b << kRngShift;
  const int tid = threadIdx.x;
  lcnt[tid] = 0;
  __syncthreads();
  const int start = rowPtr[r0];
  int rend = r0 + 256;
  if (rend > kNNodes) rend = kNNodes;
  const int end = rowPtr[rend];
  for (int e = start + tid; e < end; e += 256) {
    const int2 cv = tmpE[e];
    const int rl  = (cv.x >> 18) & 255;
    const int rank = atomicAdd(&lcnt[rl], 1);
    edgeS[rowPtr[r0 + rl] + rank] = make_int2(cv.x & 0x3FFFF, cv.y);
  }
}

// ---------------------------------------------------------------------------
// CSR SpMM, bf16 gather: one wave per row, lane = dim; 128 B/edge gather.
// ---------------------------------------------------------------------------
__global__ __launch_bounds__(256) void spmm_csr16(
    const unsigned short* __restrict__ cur16, const int* __restrict__ rowPtr,
    const int2* __restrict__ edgeS, float* __restrict__ nbuf)
{
  const int lane = threadIdx.x & 63;
  const int r = (blockIdx.x << 2) | (threadIdx.x >> 6);
  if (r >= kNNodes) return;
  const int start = __builtin_amdgcn_readfirstlane(rowPtr[r]);
  const int end   = __builtin_amdgcn_readfirstlane(rowPtr[r + 1]);
  float a0 = 0.f, a1 = 0.f, a2 = 0.f, a3 = 0.f;
  int e = start;
  for (; e + 4 <= end; e += 4) {
    const int2 cv0 = edgeS[e];
    const int2 cv1 = edgeS[e + 1];
    const int2 cv2 = edgeS[e + 2];
    const int2 cv3 = edgeS[e + 3];
    const unsigned short u0 = cur16[(size_t)cv0.x * EMB + lane];
    const unsigned short u1 = cur16[(size_t)cv1.x * EMB + lane];
    const unsigned short u2 = cur16[(size_t)cv2.x * EMB + lane];
    const unsigned short u3 = cur16[(size_t)cv3.x * EMB + lane];
    a0 = fmaf(__int_as_float(cv0.y), bf2f(u0), a0);
    a1 = fmaf(__int_as_float(cv1.y), bf2f(u1), a1);
    a2 = fmaf(__int_as_float(cv2.y), bf2f(u2), a2);
    a3 = fmaf(__int_as_float(cv3.y), bf2f(u3), a3);
  }
  for (; e < end; ++e) {
    const int2 cv = edgeS[e];
    a0 = fmaf(__int_as_float(cv.y), bf2f(cur16[(size_t)cv.x * EMB + lane]), a0);
  }
  nbuf[(size_t)r * EMB + lane] = (a0 + a1) + (a2 + a3);
}

// fp32-gather variant (fallback when ws can't hold cur16)
__global__ __launch_bounds__(256) void spmm_csr(
    const float* __restrict__ cur, const int* __restrict__ rowPtr,
    const int2* __restrict__ edgeS, float* __restrict__ nbuf)
{
  const int lane = threadIdx.x & 63;
  const int r = (blockIdx.x << 2) | (threadIdx.x >> 6);
  if (r >= kNNodes) return;
  const int start = __builtin_amdgcn_readfirstlane(rowPtr[r]);
  const int end   = __builtin_amdgcn_readfirstlane(rowPtr[r + 1]);
  float a0 = 0.f, a1 = 0.f, a2 = 0.f, a3 = 0.f;
  int e = start;
  for (; e + 4 <= end; e += 4) {
    const int2 cv0 = edgeS[e];
    const int2 cv1 = edgeS[e + 1];
    const int2 cv2 = edgeS[e + 2];
    const int2 cv3 = edgeS[e + 3];
    a0 = fmaf(__int_as_float(cv0.y), cur[(size_t)cv0.x * EMB + lane], a0);
    a1 = fmaf(__int_as_float(cv1.y), cur[(size_t)cv1.x * EMB + lane], a1);
    a2 = fmaf(__int_as_float(cv2.y), cur[(size_t)cv2.x * EMB + lane], a2);
    a3 = fmaf(__int_as_float(cv3.y), cur[(size_t)cv3.x * EMB + lane], a3);
  }
  for (; e < end; ++e) {
    const int2 cv = edgeS[e];
    a0 = fmaf(__int_as_float(cv.y), cur[(size_t)cv.x * EMB + lane], a0);
  }
  nbuf[(size_t)r * EMB + lane] = (a0 + a1) + (a2 + a3);
}

__global__ __launch_bounds__(256) void spmm_atomic(
    const float* __restrict__ cur, const int* __restrict__ rows,
    const int* __restrict__ cols, const float* __restrict__ vals,
    float* __restrict__ nbuf)
{
  const int lane = threadIdx.x & 63;
  int wv = (blockIdx.x << 2) | (threadIdx.x >> 6);
  wv = __builtin_amdgcn_readfirstlane(wv);
  int e0 = wv * kEPW;
  int e1 = e0 + kEPW;
  if (e1 > kNEdges) e1 = kNEdges;
  for (int e = e0; e < e1; ++e) {
    atomicAdd(nbuf + (size_t)rows[e] * EMB + lane,
              vals[e] * cur[(size_t)cols[e] * EMB + lane]);
  }
}

// ---------------------------------------------------------------------------
// Fused per-node transform — unchanged.
// ---------------------------------------------------------------------------
__global__ __launch_bounds__(256) void transform_inplace(
    float* __restrict__ cur, const float* __restrict__ nbuf,
    const float* __restrict__ W1, const float* __restrict__ b1,
    const float* __restrict__ W2, const float* __restrict__ b2)
{
  const int node = blockIdx.x * 256 + threadIdx.x;
  if (node >= kNNodes) return;

  const float4* __restrict__ xr  = (const float4*)(cur  + (size_t)node * EMB);
  const float4* __restrict__ nr  = (const float4*)(nbuf + (size_t)node * EMB);
  const float4* __restrict__ b1v = (const float4*)b1;
  const float4* __restrict__ b2v = (const float4*)b2;

  float4 acc1[16], acc2[16];
#pragma unroll
  for (int j = 0; j < 16; ++j) { acc1[j] = b1v[j]; acc2[j] = b2v[j]; }

#pragma unroll 2
  for (int k4 = 0; k4 < 16; ++k4) {
    const float4 xv = xr[k4];
    const float4 nv = nr[k4];
#pragma unroll
    for (int kk = 0; kk < 4; ++kk) {
      const int k = 4 * k4 + kk;
      const float xs = f4c(xv, kk);
      const float ns = f4c(nv, kk);
      const float4* __restrict__ w1r = (const float4*)(W1 + k * EMB);
      const float4* __restrict__ w2r = (const float4*)(W2 + k * EMB);
#pragma unroll
      for (int j = 0; j < 16; ++j) {
        acc1[j] = f4fma(xs, w1r[j], acc1[j]);
        acc2[j] = f4fma(ns, w2r[j], acc2[j]);
      }
    }
  }

#pragma unroll
  for (int k4 = 0; k4 < 16; ++k4) {
    const float4 xv = xr[k4];
    const float4 tv = acc2[k4];
#pragma unroll
    for (int kk = 0; kk < 4; ++kk) {
      const float ms = f4c(tv, kk) * f4c(xv, kk);
      const float4* __restrict__ w2r = (const float4*)(W2 + (4 * k4 + kk) * EMB);
#pragma unroll
      for (int j = 0; j < 16; ++j) acc1[j] = f4fma(ms, w2r[j], acc1[j]);
    }
  }

  float4* __restrict__ outp = (float4*)(cur + (size_t)node * EMB);
#pragma unroll
  for (int j = 0; j < 16; ++j) {
    float4 r;
    r.x = lrelu(acc1[j].x + acc2[j].x + b2v[j].x);
    r.y = lrelu(acc1[j].y + acc2[j].y + b2v[j].y);
    r.z = lrelu(acc1[j].z + acc2[j].z + b2v[j].z);
    r.w = lrelu(acc1[j].w + acc2[j].w + b2v[j].w);
    outp[j] = r;
  }
}

// ---------------------------------------------------------------------------
__global__ __launch_bounds__(256) void gather_out(
    const float* __restrict__ cur, const int* __restrict__ users,
    const int* __restrict__ pos, const int* __restrict__ neg,
    float* __restrict__ out, int layer)
{
  const int t    = blockIdx.x * 256 + threadIdx.x;
  const int lane = t & 63;
  const int rid  = t >> 6;
  if (rid >= 3 * kBatch) return;
  const int seg = rid / kBatch;
  const int b   = rid - seg * kBatch;
  int idx;
  if (seg == 0)      idx = users[b];
  else if (seg == 1) idx = pos[b] + kNUsers;
  else               idx = neg[b] + kNUsers;
  out[(size_t)rid * 256 + layer * EMB + lane] = cur[(size_t)idx * EMB + lane];
}

// ---------------------------------------------------------------------------
extern "C" void kernel_launch(void* const* d_in, const int* in_sizes, int n_in,
                              void* d_out, int out_size, void* d_ws, size_t ws_size,
                              hipStream_t stream) {
  const int*   users    = (const int*)d_in[0];
  const int*   pos      = (const int*)d_in[1];
  const int*   neg      = (const int*)d_in[2];
  const int*   rows     = (const int*)d_in[3];
  const int*   cols     = (const int*)d_in[4];
  const float* vals     = (const float*)d_in[5];
  const float* user_emb = (const float*)d_in[6];
  const float* item_emb = (const float*)d_in[7];
  const float* W1s      = (const float*)d_in[8];
  const float* b1s      = (const float*)d_in[9];
  const float* W2s      = (const float*)d_in[10];
  const float* b2s      = (const float*)d_in[11];
  float* out = (float*)d_out;

  const size_t nodeF = (size_t)kNNodes * EMB;
  float* cur  = (float*)d_ws;                               // 38.4 MB
  float* nbuf = cur + nodeF;                                // 38.4 MB (tmpE alias)
  int2*  edgeS     = (int2*)(nbuf + nodeF);                 // 38.4 MB
  int*   rowPtr    = (int*)(edgeS + kNEdges);               // 600 KB (+1)
  int*   rowCnt    = rowPtr + (kNNodes + 1);                // 600 KB
  int*   blockSums = rowCnt + kNNodes;                      // 2.3 KB
  int*   rangeCnt  = blockSums + kScanB;                    // 2.3 KB
  unsigned short* cur16 = (unsigned short*)(rangeCnt + kNRanges);  // 19.2 MB
  int2*  tmpE = (int2*)nbuf;                                // binned records
  const size_t neededCsr = (size_t)((char*)cur16 - (char*)d_ws);
  const size_t needed16  = neededCsr + nodeF * sizeof(unsigned short);
  const bool useCsr = ws_size >= neededCsr;
  const bool use16  = useCsr && ws_size >= needed16;

  const dim3 blk(256);
  const int iblocks = (int)((nodeF / 4 + 255) / 256);       // 9375
  const int gblocks = (3 * kBatch * EMB + 255) / 256;       // 12288
  const int eblocks = (kNEdges + 255) / 256;                // 18750
  const int rblocks = (kNNodes + 3) / 4;                    // 37500
  const int tblocks = (kNNodes + 255) / 256;                // 586

  init_embed<<<iblocks, blk, 0, stream>>>(user_emb, item_emb, cur, cur16,
                                          use16 ? 1 : 0);

  if (useCsr) {
    // one memset covers rowCnt + blockSums + rangeCnt (contiguous)
    hipMemsetAsync(rowCnt, 0,
                   (size_t)(kNNodes + kScanB + kNRanges) * sizeof(int), stream);
    hist_rows<<<eblocks, blk, 0, stream>>>(rows, rowCnt);
    scan1<<<kScanB, blk, 0, stream>>>(rowCnt, rowPtr, blockSums);
    scan2<<<1, 1024, 0, stream>>>(blockSums);
    scan3<<<kScanB, blk, 0, stream>>>(rowPtr, blockSums);
    bin_edges<<<kBinBlocks, blk, 0, stream>>>(rows, cols, vals, rowPtr,
                                              rangeCnt, tmpE);
    place_edges<<<kNRanges, blk, 0, stream>>>(tmpE, rowPtr, edgeS);
  }

  gather_out<<<gblocks, blk, 0, stream>>>(cur, users, pos, neg, out, 0);

  for (int L = 0; L < kLayers; ++L) {
    if (useCsr) {
      if (use16)
        spmm_csr16<<<rblocks, blk, 0, stream>>>(cur16, rowPtr, edgeS, nbuf);
      else
        spmm_csr<<<rblocks, blk, 0, stream>>>(cur, rowPtr, edgeS, nbuf);
    } else {
      hipMemsetAsync(nbuf, 0, nodeF * sizeof(float), stream);
      const int sblocks = (((kNEdges + kEPW - 1) / kEPW) + 3) / 4;
      spmm_atomic<<<sblocks, blk, 0, stream>>>(cur, rows, cols, vals, nbuf);
    }
    transform_inplace<<<tblocks, blk, 0, stream>>>(
        cur, nbuf, W1s + L * EMB * EMB, b1s + L * EMB,
        W2s + L * EMB * EMB, b2s + L * EMB);
    if (use16 && L + 1 < kLayers)
      refresh16<<<iblocks, blk, 0, stream>>>(cur, cur16);
    gather_out<<<gblocks, blk, 0, stream>>>(cur, users, pos, neg, out, L + 1);
  }
}

// Round 4
// 1464.466 us; speedup vs baseline: 2.0160x; 1.0744x over previous
//
#include <hip/hip_runtime.h>

// NGCF forward on gfx950 — round 10: split transform_inplace.
// R9 post-mortem: transform kept 128 floats of accumulators (acc1[16]+
// acc2[16] float4) but rocprof shows VGPR_Count=96 -> the arrays were in
// scratch (SROA bailed), WRITE_SIZE 166MB vs 38.4 ideal = spill traffic,
// 192us vs ~25us compute floor. Fix: two kernels, each with ONE 16xfloat4
// accumulator in NAMED registers (macro-expanded, no array -> no alloca):
//   transform_nbr : t = n@W2 + b2            (in-place over nbuf)
//   transform_self: cur = lrelu(x@W1 + b1+b2 + (t*x)@W2 + t)
// Weight rows are wave-uniform -> SGPR loads; ~90-120 VGPR, no spill.

#define EMB 64

constexpr int kNUsers = 100000;
constexpr int kNItems = 50000;
constexpr int kNNodes = 150000;
constexpr int kNEdges = 4800000;
constexpr int kBatch  = 16384;
constexpr int kLayers = 3;
constexpr int kScanB  = (kNNodes + 255) / 256;   // 586 scan blocks
constexpr int kRngShift = 8;                     // 256 rows per range
constexpr int kNRanges  = (kNNodes + 255) >> 8;  // 586
constexpr int kEdgesPerBin = 16384;              // edges per bin block
constexpr int kBinBlocks = (kNEdges + kEdgesPerBin - 1) / kEdgesPerBin; // 293
constexpr int kEPW    = 16;                      // fallback only

__device__ __forceinline__ float f4c(const float4& v, int i) {
  return ((const float*)&v)[i];
}
__device__ __forceinline__ float4 f4fma(float s, float4 w, float4 a) {
  a.x = fmaf(s, w.x, a.x);
  a.y = fmaf(s, w.y, a.y);
  a.z = fmaf(s, w.z, a.z);
  a.w = fmaf(s, w.w, a.w);
  return a;
}
__device__ __forceinline__ float4 f4add(float4 a, float4 b) {
  a.x += b.x; a.y += b.y; a.z += b.z; a.w += b.w;
  return a;
}
__device__ __forceinline__ float lrelu(float x) { return x > 0.f ? x : 0.2f * x; }
__device__ __forceinline__ unsigned short f2bf(float f) {   // RNE
  unsigned int u = __float_as_uint(f);
  u = (u + 0x7fffu + ((u >> 16) & 1u)) >> 16;
  return (unsigned short)u;
}
__device__ __forceinline__ float bf2f(unsigned short h) {
  return __uint_as_float(((unsigned int)h) << 16);
}

#define F16(M) M(0) M(1) M(2) M(3) M(4) M(5) M(6) M(7) \
               M(8) M(9) M(10) M(11) M(12) M(13) M(14) M(15)

// ---------------------------------------------------------------------------
// init: cur = concat(user_emb, item_emb); cur16 = bf16(cur).
// ---------------------------------------------------------------------------
__global__ __launch_bounds__(256) void init_embed(
    const float* __restrict__ user_emb, const float* __restrict__ item_emb,
    float* __restrict__ cur, unsigned short* __restrict__ cur16, int with16)
{
  const size_t userF = (size_t)kNUsers * EMB;
  const size_t allF4 = (size_t)kNNodes * EMB / 4;
  const size_t i = (size_t)blockIdx.x * 256 + threadIdx.x;
  if (i >= allF4) return;
  const size_t f = i * 4;
  const float4 v = (f < userF) ? ((const float4*)user_emb)[i]
                               : ((const float4*)(item_emb))[(f - userF) / 4];
  ((float4*)cur)[i] = v;
  if (with16) {
    ushort4 h;
    h.x = f2bf(v.x); h.y = f2bf(v.y); h.z = f2bf(v.z); h.w = f2bf(v.w);
    ((ushort4*)cur16)[i] = h;
  }
}

// Streaming bf16 shadow refresh: cur16 = bf16(cur).
__global__ __launch_bounds__(256) void refresh16(
    const float* __restrict__ cur, unsigned short* __restrict__ cur16)
{
  const size_t allF4 = (size_t)kNNodes * EMB / 4;
  const size_t i = (size_t)blockIdx.x * 256 + threadIdx.x;
  if (i >= allF4) return;
  const float4 v = ((const float4*)cur)[i];
  ushort4 h;
  h.x = f2bf(v.x); h.y = f2bf(v.y); h.z = f2bf(v.z); h.w = f2bf(v.w);
  ((ushort4*)cur16)[i] = h;
}

// ---------------------------------------------------------------------------
// CSR build (hist + 3-phase scan + hierarchical binning — unchanged from R9)
// ---------------------------------------------------------------------------
__global__ __launch_bounds__(256) void hist_rows(
    const int* __restrict__ rows, int* __restrict__ rowCnt)
{
  const int e = blockIdx.x * 256 + threadIdx.x;
  if (e < kNEdges) atomicAdd(&rowCnt[rows[e]], 1);
}

__global__ __launch_bounds__(256) void scan1(
    int* __restrict__ rowCnt, int* __restrict__ rowPtr,
    int* __restrict__ blockSums)
{
  __shared__ int wsum[4];
  const int tid  = threadIdx.x;
  const int lane = tid & 63;
  const int wid  = tid >> 6;
  const int i    = blockIdx.x * 256 + tid;
  const int cnt  = (i < kNNodes) ? rowCnt[i] : 0;
  int v = cnt;
#pragma unroll
  for (int off = 1; off < 64; off <<= 1) {
    const int n = __shfl_up(v, off, 64);
    if (lane >= off) v += n;
  }
  if (lane == 63) wsum[wid] = v;
  __syncthreads();
  if (tid == 0) {
    int s = 0;
#pragma unroll
    for (int w = 0; w < 4; ++w) { const int t = wsum[w]; wsum[w] = s; s += t; }
    blockSums[blockIdx.x] = s;
  }
  __syncthreads();
  if (i < kNNodes) {
    rowPtr[i] = wsum[wid] + v - cnt;
    rowCnt[i] = 0;
  }
}

__global__ __launch_bounds__(1024) void scan2(int* __restrict__ blockSums)
{
  __shared__ int wsum[16];
  const int tid  = threadIdx.x;
  const int lane = tid & 63;
  const int wid  = tid >> 6;
  const int cnt  = (tid < kScanB) ? blockSums[tid] : 0;
  int v = cnt;
#pragma unroll
  for (int off = 1; off < 64; off <<= 1) {
    const int n = __shfl_up(v, off, 64);
    if (lane >= off) v += n;
  }
  if (lane == 63) wsum[wid] = v;
  __syncthreads();
  if (tid == 0) {
    int s = 0;
#pragma unroll
    for (int w = 0; w < 16; ++w) { const int t = wsum[w]; wsum[w] = s; s += t; }
  }
  __syncthreads();
  if (tid < kScanB) blockSums[tid] = wsum[wid] + v - cnt;
}

__global__ __launch_bounds__(256) void scan3(
    int* __restrict__ rowPtr, const int* __restrict__ blockSums)
{
  const int i = blockIdx.x * 256 + threadIdx.x;
  if (i < kNNodes) rowPtr[i] += blockSums[blockIdx.x];
  if (i == 0) rowPtr[kNNodes] = kNEdges;
}

// Pass 1: bin edges into 586 row-ranges. Per block: LDS histogram, ONE
// global atomic per (block,range) reserving a contiguous burst, then scatter
// into the exclusively-owned burst. Record: col | localRow<<18.
__global__ __launch_bounds__(256) void bin_edges(
    const int* __restrict__ rows, const int* __restrict__ cols,
    const float* __restrict__ vals, const int* __restrict__ rowPtr,
    int* __restrict__ rangeCnt, int2* __restrict__ tmpE)
{
  __shared__ int cnt[kNRanges];
  __shared__ int base[kNRanges];
  const int tid = threadIdx.x;
  const int e0  = blockIdx.x * kEdgesPerBin;
  int e1 = e0 + kEdgesPerBin;
  if (e1 > kNEdges) e1 = kNEdges;

  for (int b = tid; b < kNRanges; b += 256) cnt[b] = 0;
  __syncthreads();
  for (int e = e0 + tid; e < e1; e += 256)
    atomicAdd(&cnt[rows[e] >> kRngShift], 1);
  __syncthreads();
  for (int b = tid; b < kNRanges; b += 256) {
    const int c = cnt[b];
    base[b] = (c > 0) ? (rowPtr[b << kRngShift] + atomicAdd(&rangeCnt[b], c))
                      : 0;
    cnt[b] = 0;
  }
  __syncthreads();
  for (int e = e0 + tid; e < e1; e += 256) {
    const int r = rows[e];
    const int b = r >> kRngShift;
    const int rank = atomicAdd(&cnt[b], 1);
    tmpE[base[b] + rank] =
        make_int2(cols[e] | ((r & 255) << 18), __float_as_int(vals[e]));
  }
}

// Pass 2: one WG per range. Src slab and dst CSR window both L2-resident;
// LDS rank counters give exact CSR slots.
__global__ __launch_bounds__(256) void place_edges(
    const int2* __restrict__ tmpE, const int* __restrict__ rowPtr,
    int2* __restrict__ edgeS)
{
  __shared__ int lcnt[256];
  const int b   = blockIdx.x;
  const int r0  = b << kRngShift;
  const int tid = threadIdx.x;
  lcnt[tid] = 0;
  __syncthreads();
  const int start = rowPtr[r0];
  int rend = r0 + 256;
  if (rend > kNNodes) rend = kNNodes;
  const int end = rowPtr[rend];
  for (int e = start + tid; e < end; e += 256) {
    const int2 cv = tmpE[e];
    const int rl  = (cv.x >> 18) & 255;
    const int rank = atomicAdd(&lcnt[rl], 1);
    edgeS[rowPtr[r0 + rl] + rank] = make_int2(cv.x & 0x3FFFF, cv.y);
  }
}

// ---------------------------------------------------------------------------
// CSR SpMM, bf16 gather: one wave per row, lane = dim; 128 B/edge gather.
// ---------------------------------------------------------------------------
__global__ __launch_bounds__(256) void spmm_csr16(
    const unsigned short* __restrict__ cur16, const int* __restrict__ rowPtr,
    const int2* __restrict__ edgeS, float* __restrict__ nbuf)
{
  const int lane = threadIdx.x & 63;
  const int r = (blockIdx.x << 2) | (threadIdx.x >> 6);
  if (r >= kNNodes) return;
  const int start = __builtin_amdgcn_readfirstlane(rowPtr[r]);
  const int end   = __builtin_amdgcn_readfirstlane(rowPtr[r + 1]);
  float a0 = 0.f, a1 = 0.f, a2 = 0.f, a3 = 0.f;
  int e = start;
  for (; e + 4 <= end; e += 4) {
    const int2 cv0 = edgeS[e];
    const int2 cv1 = edgeS[e + 1];
    const int2 cv2 = edgeS[e + 2];
    const int2 cv3 = edgeS[e + 3];
    const unsigned short u0 = cur16[(size_t)cv0.x * EMB + lane];
    const unsigned short u1 = cur16[(size_t)cv1.x * EMB + lane];
    const unsigned short u2 = cur16[(size_t)cv2.x * EMB + lane];
    const unsigned short u3 = cur16[(size_t)cv3.x * EMB + lane];
    a0 = fmaf(__int_as_float(cv0.y), bf2f(u0), a0);
    a1 = fmaf(__int_as_float(cv1.y), bf2f(u1), a1);
    a2 = fmaf(__int_as_float(cv2.y), bf2f(u2), a2);
    a3 = fmaf(__int_as_float(cv3.y), bf2f(u3), a3);
  }
  for (; e < end; ++e) {
    const int2 cv = edgeS[e];
    a0 = fmaf(__int_as_float(cv.y), bf2f(cur16[(size_t)cv.x * EMB + lane]), a0);
  }
  nbuf[(size_t)r * EMB + lane] = (a0 + a1) + (a2 + a3);
}

// fp32-gather variant (fallback when ws can't hold cur16)
__global__ __launch_bounds__(256) void spmm_csr(
    const float* __restrict__ cur, const int* __restrict__ rowPtr,
    const int2* __restrict__ edgeS, float* __restrict__ nbuf)
{
  const int lane = threadIdx.x & 63;
  const int r = (blockIdx.x << 2) | (threadIdx.x >> 6);
  if (r >= kNNodes) return;
  const int start = __builtin_amdgcn_readfirstlane(rowPtr[r]);
  const int end   = __builtin_amdgcn_readfirstlane(rowPtr[r + 1]);
  float a0 = 0.f, a1 = 0.f, a2 = 0.f, a3 = 0.f;
  int e = start;
  for (; e + 4 <= end; e += 4) {
    const int2 cv0 = edgeS[e];
    const int2 cv1 = edgeS[e + 1];
    const int2 cv2 = edgeS[e + 2];
    const int2 cv3 = edgeS[e + 3];
    a0 = fmaf(__int_as_float(cv0.y), cur[(size_t)cv0.x * EMB + lane], a0);
    a1 = fmaf(__int_as_float(cv1.y), cur[(size_t)cv1.x * EMB + lane], a1);
    a2 = fmaf(__int_as_float(cv2.y), cur[(size_t)cv2.x * EMB + lane], a2);
    a3 = fmaf(__int_as_float(cv3.y), cur[(size_t)cv3.x * EMB + lane], a3);
  }
  for (; e < end; ++e) {
    const int2 cv = edgeS[e];
    a0 = fmaf(__int_as_float(cv.y), cur[(size_t)cv.x * EMB + lane], a0);
  }
  nbuf[(size_t)r * EMB + lane] = (a0 + a1) + (a2 + a3);
}

__global__ __launch_bounds__(256) void spmm_atomic(
    const float* __restrict__ cur, const int* __restrict__ rows,
    const int* __restrict__ cols, const float* __restrict__ vals,
    float* __restrict__ nbuf)
{
  const int lane = threadIdx.x & 63;
  int wv = (blockIdx.x << 2) | (threadIdx.x >> 6);
  wv = __builtin_amdgcn_readfirstlane(wv);
  int e0 = wv * kEPW;
  int e1 = e0 + kEPW;
  if (e1 > kNEdges) e1 = kNEdges;
  for (int e = e0; e < e1; ++e) {
    atomicAdd(nbuf + (size_t)rows[e] * EMB + lane,
              vals[e] * cur[(size_t)cols[e] * EMB + lane]);
  }
}

// ---------------------------------------------------------------------------
// Transform pass 1: t = n@W2 + b2, in place over nbuf.
// ONE accumulator set in NAMED registers (no array -> no scratch).
// ---------------------------------------------------------------------------
__global__ __launch_bounds__(256) void transform_nbr(
    float* __restrict__ nbuf, const float* __restrict__ W2,
    const float* __restrict__ b2)
{
  const int node = blockIdx.x * 256 + threadIdx.x;
  if (node >= kNNodes) return;
  const float4* __restrict__ nr  = (const float4*)(nbuf + (size_t)node * EMB);
  const float4* __restrict__ b2v = (const float4*)b2;
#define DECL(j) float4 a##j = b2v[j];
  F16(DECL)
#undef DECL
#pragma unroll 4
  for (int k4 = 0; k4 < 16; ++k4) {
    const float4 nv = nr[k4];
#pragma unroll
    for (int kk = 0; kk < 4; ++kk) {
      const float ns = f4c(nv, kk);
      const float4* __restrict__ w2r = (const float4*)(W2 + (4 * k4 + kk) * EMB);
#define STEP(j) a##j = f4fma(ns, w2r[j], a##j);
      F16(STEP)
#undef STEP
    }
  }
  float4* __restrict__ outp = (float4*)(nbuf + (size_t)node * EMB);
#define STORE(j) outp[j] = a##j;
  F16(STORE)
#undef STORE
}

// ---------------------------------------------------------------------------
// Transform pass 2: cur = lrelu(x@W1 + b1 + b2 + (t*x)@W2 + t), t from nbuf.
// ---------------------------------------------------------------------------
__global__ __launch_bounds__(256) void transform_self(
    float* __restrict__ cur, const float* __restrict__ nbuf,
    const float* __restrict__ W1, const float* __restrict__ b1,
    const float* __restrict__ b2, const float* __restrict__ W2)
{
  const int node = blockIdx.x * 256 + threadIdx.x;
  if (node >= kNNodes) return;
  const float4* __restrict__ xr  = (const float4*)(cur  + (size_t)node * EMB);
  const float4* __restrict__ tr  = (const float4*)(nbuf + (size_t)node * EMB);
  const float4* __restrict__ b1v = (const float4*)b1;
  const float4* __restrict__ b2v = (const float4*)b2;
#define DECL(j) float4 a##j = f4add(b1v[j], b2v[j]);
  F16(DECL)
#undef DECL
#pragma unroll 2
  for (int k4 = 0; k4 < 16; ++k4) {
    const float4 xv = xr[k4];
    const float4 tv = tr[k4];
#pragma unroll
    for (int kk = 0; kk < 4; ++kk) {
      const float xs = f4c(xv, kk);
      const float ms = f4c(tv, kk) * xs;
      const int k = 4 * k4 + kk;
      const float4* __restrict__ w1r = (const float4*)(W1 + k * EMB);
      const float4* __restrict__ w2r = (const float4*)(W2 + k * EMB);
#define STEP(j) a##j = f4fma(xs, w1r[j], a##j); a##j = f4fma(ms, w2r[j], a##j);
      F16(STEP)
#undef STEP
    }
  }
  float4* __restrict__ outp = (float4*)(cur + (size_t)node * EMB);
#define STORE(j) { const float4 tj = tr[j]; float4 r;          \
    r.x = lrelu(a##j.x + tj.x); r.y = lrelu(a##j.y + tj.y);    \
    r.z = lrelu(a##j.z + tj.z); r.w = lrelu(a##j.w + tj.w);    \
    outp[j] = r; }
  F16(STORE)
#undef STORE
}

// ---------------------------------------------------------------------------
__global__ __launch_bounds__(256) void gather_out(
    const float* __restrict__ cur, const int* __restrict__ users,
    const int* __restrict__ pos, const int* __restrict__ neg,
    float* __restrict__ out, int layer)
{
  const int t    = blockIdx.x * 256 + threadIdx.x;
  const int lane = t & 63;
  const int rid  = t >> 6;
  if (rid >= 3 * kBatch) return;
  const int seg = rid / kBatch;
  const int b   = rid - seg * kBatch;
  int idx;
  if (seg == 0)      idx = users[b];
  else if (seg == 1) idx = pos[b] + kNUsers;
  else               idx = neg[b] + kNUsers;
  out[(size_t)rid * 256 + layer * EMB + lane] = cur[(size_t)idx * EMB + lane];
}

// ---------------------------------------------------------------------------
extern "C" void kernel_launch(void* const* d_in, const int* in_sizes, int n_in,
                              void* d_out, int out_size, void* d_ws, size_t ws_size,
                              hipStream_t stream) {
  const int*   users    = (const int*)d_in[0];
  const int*   pos      = (const int*)d_in[1];
  const int*   neg      = (const int*)d_in[2];
  const int*   rows     = (const int*)d_in[3];
  const int*   cols     = (const int*)d_in[4];
  const float* vals     = (const float*)d_in[5];
  const float* user_emb = (const float*)d_in[6];
  const float* item_emb = (const float*)d_in[7];
  const float* W1s      = (const float*)d_in[8];
  const float* b1s      = (const float*)d_in[9];
  const float* W2s      = (const float*)d_in[10];
  const float* b2s      = (const float*)d_in[11];
  float* out = (float*)d_out;

  const size_t nodeF = (size_t)kNNodes * EMB;
  float* cur  = (float*)d_ws;                               // 38.4 MB
  float* nbuf = cur + nodeF;                                // 38.4 MB (tmpE alias)
  int2*  edgeS     = (int2*)(nbuf + nodeF);                 // 38.4 MB
  int*   rowPtr    = (int*)(edgeS + kNEdges);               // 600 KB (+1)
  int*   rowCnt    = rowPtr + (kNNodes + 1);                // 600 KB
  int*   blockSums = rowCnt + kNNodes;                      // 2.3 KB
  int*   rangeCnt  = blockSums + kScanB;                    // 2.3 KB
  unsigned short* cur16 = (unsigned short*)(rangeCnt + kNRanges);  // 19.2 MB
  int2*  tmpE = (int2*)nbuf;                                // binned records
  const size_t neededCsr = (size_t)((char*)cur16 - (char*)d_ws);
  const size_t needed16  = neededCsr + nodeF * sizeof(unsigned short);
  const bool useCsr = ws_size >= neededCsr;
  const bool use16  = useCsr && ws_size >= needed16;

  const dim3 blk(256);
  const int iblocks = (int)((nodeF / 4 + 255) / 256);       // 9375
  const int gblocks = (3 * kBatch * EMB + 255) / 256;       // 12288
  const int eblocks = (kNEdges + 255) / 256;                // 18750
  const int rblocks = (kNNodes + 3) / 4;                    // 37500
  const int tblocks = (kNNodes + 255) / 256;                // 586

  init_embed<<<iblocks, blk, 0, stream>>>(user_emb, item_emb, cur, cur16,
                                          use16 ? 1 : 0);

  if (useCsr) {
    // one memset covers rowCnt + blockSums + rangeCnt (contiguous)
    hipMemsetAsync(rowCnt, 0,
                   (size_t)(kNNodes + kScanB + kNRanges) * sizeof(int), stream);
    hist_rows<<<eblocks, blk, 0, stream>>>(rows, rowCnt);
    scan1<<<kScanB, blk, 0, stream>>>(rowCnt, rowPtr, blockSums);
    scan2<<<1, 1024, 0, stream>>>(blockSums);
    scan3<<<kScanB, blk, 0, stream>>>(rowPtr, blockSums);
    bin_edges<<<kBinBlocks, blk, 0, stream>>>(rows, cols, vals, rowPtr,
                                              rangeCnt, tmpE);
    place_edges<<<kNRanges, blk, 0, stream>>>(tmpE, rowPtr, edgeS);
  }

  gather_out<<<gblocks, blk, 0, stream>>>(cur, users, pos, neg, out, 0);

  for (int L = 0; L < kLayers; ++L) {
    if (useCsr) {
      if (use16)
        spmm_csr16<<<rblocks, blk, 0, stream>>>(cur16, rowPtr, edgeS, nbuf);
      else
        spmm_csr<<<rblocks, blk, 0, stream>>>(cur, rowPtr, edgeS, nbuf);
    } else {
      hipMemsetAsync(nbuf, 0, nodeF * sizeof(float), stream);
      const int sblocks = (((kNEdges + kEPW - 1) / kEPW) + 3) / 4;
      spmm_atomic<<<sblocks, blk, 0, stream>>>(cur, rows, cols, vals, nbuf);
    }
    transform_nbr<<<tblocks, blk, 0, stream>>>(
        nbuf, W2s + L * EMB * EMB, b2s + L * EMB);
    transform_self<<<tblocks, blk, 0, stream>>>(
        cur, nbuf, W1s + L * EMB * EMB, b1s + L * EMB,
        b2s + L * EMB, W2s + L * EMB * EMB);
    if (use16 && L + 1 < kLayers)
      refresh16<<<iblocks, blk, 0, stream>>>(cur, cur16);
    gather_out<<<gblocks, blk, 0, stream>>>(cur, users, pos, neg, out, L + 1);
  }
}

// Round 5
// 1312.223 us; speedup vs baseline: 2.2499x; 1.1160x over previous
//
#include <hip/hip_runtime.h>

// NGCF forward on gfx950 — round 11: kill the per-row global histogram.
// R10 post-mortem: hist_rows = 187us, WRITE_SIZE 150MB for 600KB of counters
// — 4.8M device atomics each forcing a ~31B memory-side writeback (per-XCD
// L2s can't cache the RMW). Fix: the binning pipeline never needed per-row
// counts globally: (1) hist_ranges does an LDS histogram over 586 ranges and
// ONE atomic per (block,range) = 172K atomics; (2) scan_ranges (1 block)
// scans the 586 totals; (3) bin_edges reserves bursts off rangeStart;
// (4) place_edges derives per-row CSR locally (LDS hist + block scan of its
// 256 rows over the L2-resident slab) and writes rowPtr itself.
// hist_rows + scan1/scan3 (150K-row scan) are deleted.

#define EMB 64

constexpr int kNUsers = 100000;
constexpr int kNItems = 50000;
constexpr int kNNodes = 150000;
constexpr int kNEdges = 4800000;
constexpr int kBatch  = 16384;
constexpr int kLayers = 3;
constexpr int kRngShift = 8;                     // 256 rows per range
constexpr int kNRanges  = (kNNodes + 255) >> 8;  // 586
constexpr int kEdgesPerBin = 16384;              // edges per bin block
constexpr int kBinBlocks = (kNEdges + kEdgesPerBin - 1) / kEdgesPerBin; // 293
constexpr int kEPW    = 16;                      // fallback only

__device__ __forceinline__ float f4c(const float4& v, int i) {
  return ((const float*)&v)[i];
}
__device__ __forceinline__ float4 f4fma(float s, float4 w, float4 a) {
  a.x = fmaf(s, w.x, a.x);
  a.y = fmaf(s, w.y, a.y);
  a.z = fmaf(s, w.z, a.z);
  a.w = fmaf(s, w.w, a.w);
  return a;
}
__device__ __forceinline__ float4 f4add(float4 a, float4 b) {
  a.x += b.x; a.y += b.y; a.z += b.z; a.w += b.w;
  return a;
}
__device__ __forceinline__ float lrelu(float x) { return x > 0.f ? x : 0.2f * x; }
__device__ __forceinline__ unsigned short f2bf(float f) {   // RNE
  unsigned int u = __float_as_uint(f);
  u = (u + 0x7fffu + ((u >> 16) & 1u)) >> 16;
  return (unsigned short)u;
}
__device__ __forceinline__ float bf2f(unsigned short h) {
  return __uint_as_float(((unsigned int)h) << 16);
}

#define F16(M) M(0) M(1) M(2) M(3) M(4) M(5) M(6) M(7) \
               M(8) M(9) M(10) M(11) M(12) M(13) M(14) M(15)

// ---------------------------------------------------------------------------
// init: cur = concat(user_emb, item_emb); cur16 = bf16(cur).
// ---------------------------------------------------------------------------
__global__ __launch_bounds__(256) void init_embed(
    const float* __restrict__ user_emb, const float* __restrict__ item_emb,
    float* __restrict__ cur, unsigned short* __restrict__ cur16, int with16)
{
  const size_t userF = (size_t)kNUsers * EMB;
  const size_t allF4 = (size_t)kNNodes * EMB / 4;
  const size_t i = (size_t)blockIdx.x * 256 + threadIdx.x;
  if (i >= allF4) return;
  const size_t f = i * 4;
  const float4 v = (f < userF) ? ((const float4*)user_emb)[i]
                               : ((const float4*)(item_emb))[(f - userF) / 4];
  ((float4*)cur)[i] = v;
  if (with16) {
    ushort4 h;
    h.x = f2bf(v.x); h.y = f2bf(v.y); h.z = f2bf(v.z); h.w = f2bf(v.w);
    ((ushort4*)cur16)[i] = h;
  }
}

// Streaming bf16 shadow refresh: cur16 = bf16(cur).
__global__ __launch_bounds__(256) void refresh16(
    const float* __restrict__ cur, unsigned short* __restrict__ cur16)
{
  const size_t allF4 = (size_t)kNNodes * EMB / 4;
  const size_t i = (size_t)blockIdx.x * 256 + threadIdx.x;
  if (i >= allF4) return;
  const float4 v = ((const float4*)cur)[i];
  ushort4 h;
  h.x = f2bf(v.x); h.y = f2bf(v.y); h.z = f2bf(v.z); h.w = f2bf(v.w);
  ((ushort4*)cur16)[i] = h;
}

// ---------------------------------------------------------------------------
// CSR build: range histogram -> range scan -> burst binning -> local place.
// ---------------------------------------------------------------------------

// Per-block LDS histogram over 586 ranges; one global atomic per (block,range).
__global__ __launch_bounds__(256) void hist_ranges(
    const int* __restrict__ rows, int* __restrict__ rangeA)
{
  __shared__ int cnt[kNRanges];
  const int tid = threadIdx.x;
  const int e0  = blockIdx.x * kEdgesPerBin;
  int e1 = e0 + kEdgesPerBin;
  if (e1 > kNEdges) e1 = kNEdges;
  for (int b = tid; b < kNRanges; b += 256) cnt[b] = 0;
  __syncthreads();
  for (int e = e0 + tid; e < e1; e += 256)
    atomicAdd(&cnt[rows[e] >> kRngShift], 1);
  __syncthreads();
  for (int b = tid; b < kNRanges; b += 256)
    if (cnt[b] > 0) atomicAdd(&rangeA[b], cnt[b]);
}

// Exclusive scan of the 586 range totals, in place (1 block).
__global__ __launch_bounds__(1024) void scan_ranges(
    int* __restrict__ rangeA, int* __restrict__ rowPtr)
{
  __shared__ int wsum[16];
  const int tid  = threadIdx.x;
  const int lane = tid & 63;
  const int wid  = tid >> 6;
  const int cnt  = (tid < kNRanges) ? rangeA[tid] : 0;
  int v = cnt;
#pragma unroll
  for (int off = 1; off < 64; off <<= 1) {
    const int n = __shfl_up(v, off, 64);
    if (lane >= off) v += n;
  }
  if (lane == 63) wsum[wid] = v;
  __syncthreads();
  if (tid == 0) {
    int s = 0;
#pragma unroll
    for (int w = 0; w < 16; ++w) { const int t = wsum[w]; wsum[w] = s; s += t; }
  }
  __syncthreads();
  if (tid < kNRanges) rangeA[tid] = wsum[wid] + v - cnt;
  if (tid == 0) {
    rangeA[kNRanges]  = kNEdges;
    rowPtr[kNNodes]   = kNEdges;
  }
}

// Bin edges into 586 row-ranges. Per block: LDS histogram, ONE global atomic
// per (block,range) reserving a contiguous burst off rangeStart, then scatter
// into the exclusively-owned burst. Record: col | localRow<<18.
__global__ __launch_bounds__(256) void bin_edges(
    const int* __restrict__ rows, const int* __restrict__ cols,
    const float* __restrict__ vals, const int* __restrict__ rangeA,
    int* __restrict__ rangeCnt, int2* __restrict__ tmpE)
{
  __shared__ int cnt[kNRanges];
  __shared__ int base[kNRanges];
  const int tid = threadIdx.x;
  const int e0  = blockIdx.x * kEdgesPerBin;
  int e1 = e0 + kEdgesPerBin;
  if (e1 > kNEdges) e1 = kNEdges;

  for (int b = tid; b < kNRanges; b += 256) cnt[b] = 0;
  __syncthreads();
  for (int e = e0 + tid; e < e1; e += 256)
    atomicAdd(&cnt[rows[e] >> kRngShift], 1);
  __syncthreads();
  for (int b = tid; b < kNRanges; b += 256) {
    const int c = cnt[b];
    base[b] = (c > 0) ? (rangeA[b] + atomicAdd(&rangeCnt[b], c)) : 0;
    cnt[b] = 0;
  }
  __syncthreads();
  for (int e = e0 + tid; e < e1; e += 256) {
    const int r = rows[e];
    const int b = r >> kRngShift;
    const int rank = atomicAdd(&cnt[b], 1);
    tmpE[base[b] + rank] =
        make_int2(cols[e] | ((r & 255) << 18), __float_as_int(vals[e]));
  }
}

// One WG per range: derive local per-row CSR (LDS hist + block scan over the
// L2-resident slab), write rowPtr for its 256 rows, then place each edge at
// its exact CSR slot. Every edgeS line written exactly once.
__global__ __launch_bounds__(256) void place_edges(
    const int2* __restrict__ tmpE, const int* __restrict__ rangeA,
    int2* __restrict__ edgeS, int* __restrict__ rowPtr)
{
  __shared__ int lcnt[256];
  __shared__ int lbase[256];
  __shared__ int ws[4];
  const int b    = blockIdx.x;
  const int r0   = b << kRngShift;
  const int tid  = threadIdx.x;
  const int lane = tid & 63;
  const int wid  = tid >> 6;
  const int start = rangeA[b];
  const int end   = rangeA[b + 1];

  lcnt[tid] = 0;
  __syncthreads();
  for (int e = start + tid; e < end; e += 256)
    atomicAdd(&lcnt[(tmpE[e].x >> 18) & 255], 1);
  __syncthreads();

  const int c = lcnt[tid];        // own count (read before reset)
  int v = c;
#pragma unroll
  for (int off = 1; off < 64; off <<= 1) {
    const int n = __shfl_up(v, off, 64);
    if (lane >= off) v += n;
  }
  if (lane == 63) ws[wid] = v;
  __syncthreads();
  int wadd = 0;
#pragma unroll
  for (int w = 0; w < 4; ++w) if (w < wid) wadd += ws[w];
  const int excl = v - c + wadd;  // exclusive local prefix
  lbase[tid] = start + excl;
  if (r0 + tid < kNNodes) rowPtr[r0 + tid] = start + excl;
  lcnt[tid] = 0;
  __syncthreads();

  for (int e = start + tid; e < end; e += 256) {
    const int2 cv = tmpE[e];
    const int rl  = (cv.x >> 18) & 255;
    const int rank = atomicAdd(&lcnt[rl], 1);
    edgeS[lbase[rl] + rank] = make_int2(cv.x & 0x3FFFF, cv.y);
  }
}

// ---------------------------------------------------------------------------
// CSR SpMM, bf16 gather: one wave per row, lane = dim; 128 B/edge gather.
// ---------------------------------------------------------------------------
__global__ __launch_bounds__(256) void spmm_csr16(
    const unsigned short* __restrict__ cur16, const int* __restrict__ rowPtr,
    const int2* __restrict__ edgeS, float* __restrict__ nbuf)
{
  const int lane = threadIdx.x & 63;
  const int r = (blockIdx.x << 2) | (threadIdx.x >> 6);
  if (r >= kNNodes) return;
  const int start = __builtin_amdgcn_readfirstlane(rowPtr[r]);
  const int end   = __builtin_amdgcn_readfirstlane(rowPtr[r + 1]);
  float a0 = 0.f, a1 = 0.f, a2 = 0.f, a3 = 0.f;
  int e = start;
  for (; e + 4 <= end; e += 4) {
    const int2 cv0 = edgeS[e];
    const int2 cv1 = edgeS[e + 1];
    const int2 cv2 = edgeS[e + 2];
    const int2 cv3 = edgeS[e + 3];
    const unsigned short u0 = cur16[(size_t)cv0.x * EMB + lane];
    const unsigned short u1 = cur16[(size_t)cv1.x * EMB + lane];
    const unsigned short u2 = cur16[(size_t)cv2.x * EMB + lane];
    const unsigned short u3 = cur16[(size_t)cv3.x * EMB + lane];
    a0 = fmaf(__int_as_float(cv0.y), bf2f(u0), a0);
    a1 = fmaf(__int_as_float(cv1.y), bf2f(u1), a1);
    a2 = fmaf(__int_as_float(cv2.y), bf2f(u2), a2);
    a3 = fmaf(__int_as_float(cv3.y), bf2f(u3), a3);
  }
  for (; e < end; ++e) {
    const int2 cv = edgeS[e];
    a0 = fmaf(__int_as_float(cv.y), bf2f(cur16[(size_t)cv.x * EMB + lane]), a0);
  }
  nbuf[(size_t)r * EMB + lane] = (a0 + a1) + (a2 + a3);
}

// fp32-gather variant (fallback when ws can't hold cur16)
__global__ __launch_bounds__(256) void spmm_csr(
    const float* __restrict__ cur, const int* __restrict__ rowPtr,
    const int2* __restrict__ edgeS, float* __restrict__ nbuf)
{
  const int lane = threadIdx.x & 63;
  const int r = (blockIdx.x << 2) | (threadIdx.x >> 6);
  if (r >= kNNodes) return;
  const int start = __builtin_amdgcn_readfirstlane(rowPtr[r]);
  const int end   = __builtin_amdgcn_readfirstlane(rowPtr[r + 1]);
  float a0 = 0.f, a1 = 0.f, a2 = 0.f, a3 = 0.f;
  int e = start;
  for (; e + 4 <= end; e += 4) {
    const int2 cv0 = edgeS[e];
    const int2 cv1 = edgeS[e + 1];
    const int2 cv2 = edgeS[e + 2];
    const int2 cv3 = edgeS[e + 3];
    a0 = fmaf(__int_as_float(cv0.y), cur[(size_t)cv0.x * EMB + lane], a0);
    a1 = fmaf(__int_as_float(cv1.y), cur[(size_t)cv1.x * EMB + lane], a1);
    a2 = fmaf(__int_as_float(cv2.y), cur[(size_t)cv2.x * EMB + lane], a2);
    a3 = fmaf(__int_as_float(cv3.y), cur[(size_t)cv3.x * EMB + lane], a3);
  }
  for (; e < end; ++e) {
    const int2 cv = edgeS[e];
    a0 = fmaf(__int_as_float(cv.y), cur[(size_t)cv.x * EMB + lane], a0);
  }
  nbuf[(size_t)r * EMB + lane] = (a0 + a1) + (a2 + a3);
}

__global__ __launch_bounds__(256) void spmm_atomic(
    const float* __restrict__ cur, const int* __restrict__ rows,
    const int* __restrict__ cols, const float* __restrict__ vals,
    float* __restrict__ nbuf)
{
  const int lane = threadIdx.x & 63;
  int wv = (blockIdx.x << 2) | (threadIdx.x >> 6);
  wv = __builtin_amdgcn_readfirstlane(wv);
  int e0 = wv * kEPW;
  int e1 = e0 + kEPW;
  if (e1 > kNEdges) e1 = kNEdges;
  for (int e = e0; e < e1; ++e) {
    atomicAdd(nbuf + (size_t)rows[e] * EMB + lane,
              vals[e] * cur[(size_t)cols[e] * EMB + lane]);
  }
}

// ---------------------------------------------------------------------------
// Transform pass 1: t = n@W2 + b2, in place over nbuf. Named-register accs.
// ---------------------------------------------------------------------------
__global__ __launch_bounds__(256) void transform_nbr(
    float* __restrict__ nbuf, const float* __restrict__ W2,
    const float* __restrict__ b2)
{
  const int node = blockIdx.x * 256 + threadIdx.x;
  if (node >= kNNodes) return;
  const float4* __restrict__ nr  = (const float4*)(nbuf + (size_t)node * EMB);
  const float4* __restrict__ b2v = (const float4*)b2;
#define DECL(j) float4 a##j = b2v[j];
  F16(DECL)
#undef DECL
#pragma unroll 4
  for (int k4 = 0; k4 < 16; ++k4) {
    const float4 nv = nr[k4];
#pragma unroll
    for (int kk = 0; kk < 4; ++kk) {
      const float ns = f4c(nv, kk);
      const float4* __restrict__ w2r = (const float4*)(W2 + (4 * k4 + kk) * EMB);
#define STEP(j) a##j = f4fma(ns, w2r[j], a##j);
      F16(STEP)
#undef STEP
    }
  }
  float4* __restrict__ outp = (float4*)(nbuf + (size_t)node * EMB);
#define STORE(j) outp[j] = a##j;
  F16(STORE)
#undef STORE
}

// ---------------------------------------------------------------------------
// Transform pass 2: cur = lrelu(x@W1 + b1 + b2 + (t*x)@W2 + t), t from nbuf.
// ---------------------------------------------------------------------------
__global__ __launch_bounds__(256) void transform_self(
    float* __restrict__ cur, const float* __restrict__ nbuf,
    const float* __restrict__ W1, const float* __restrict__ b1,
    const float* __restrict__ b2, const float* __restrict__ W2)
{
  const int node = blockIdx.x * 256 + threadIdx.x;
  if (node >= kNNodes) return;
  const float4* __restrict__ xr  = (const float4*)(cur  + (size_t)node * EMB);
  const float4* __restrict__ tr  = (const float4*)(nbuf + (size_t)node * EMB);
  const float4* __restrict__ b1v = (const float4*)b1;
  const float4* __restrict__ b2v = (const float4*)b2;
#define DECL(j) float4 a##j = f4add(b1v[j], b2v[j]);
  F16(DECL)
#undef DECL
#pragma unroll 2
  for (int k4 = 0; k4 < 16; ++k4) {
    const float4 xv = xr[k4];
    const float4 tv = tr[k4];
#pragma unroll
    for (int kk = 0; kk < 4; ++kk) {
      const float xs = f4c(xv, kk);
      const float ms = f4c(tv, kk) * xs;
      const int k = 4 * k4 + kk;
      const float4* __restrict__ w1r = (const float4*)(W1 + k * EMB);
      const float4* __restrict__ w2r = (const float4*)(W2 + k * EMB);
#define STEP(j) a##j = f4fma(xs, w1r[j], a##j); a##j = f4fma(ms, w2r[j], a##j);
      F16(STEP)
#undef STEP
    }
  }
  float4* __restrict__ outp = (float4*)(cur + (size_t)node * EMB);
#define STORE(j) { const float4 tj = tr[j]; float4 r;          \
    r.x = lrelu(a##j.x + tj.x); r.y = lrelu(a##j.y + tj.y);    \
    r.z = lrelu(a##j.z + tj.z); r.w = lrelu(a##j.w + tj.w);    \
    outp[j] = r; }
  F16(STORE)
#undef STORE
}

// ---------------------------------------------------------------------------
__global__ __launch_bounds__(256) void gather_out(
    const float* __restrict__ cur, const int* __restrict__ users,
    const int* __restrict__ pos, const int* __restrict__ neg,
    float* __restrict__ out, int layer)
{
  const int t    = blockIdx.x * 256 + threadIdx.x;
  const int lane = t & 63;
  const int rid  = t >> 6;
  if (rid >= 3 * kBatch) return;
  const int seg = rid / kBatch;
  const int b   = rid - seg * kBatch;
  int idx;
  if (seg == 0)      idx = users[b];
  else if (seg == 1) idx = pos[b] + kNUsers;
  else               idx = neg[b] + kNUsers;
  out[(size_t)rid * 256 + layer * EMB + lane] = cur[(size_t)idx * EMB + lane];
}

// ---------------------------------------------------------------------------
extern "C" void kernel_launch(void* const* d_in, const int* in_sizes, int n_in,
                              void* d_out, int out_size, void* d_ws, size_t ws_size,
                              hipStream_t stream) {
  const int*   users    = (const int*)d_in[0];
  const int*   pos      = (const int*)d_in[1];
  const int*   neg      = (const int*)d_in[2];
  const int*   rows     = (const int*)d_in[3];
  const int*   cols     = (const int*)d_in[4];
  const float* vals     = (const float*)d_in[5];
  const float* user_emb = (const float*)d_in[6];
  const float* item_emb = (const float*)d_in[7];
  const float* W1s      = (const float*)d_in[8];
  const float* b1s      = (const float*)d_in[9];
  const float* W2s      = (const float*)d_in[10];
  const float* b2s      = (const float*)d_in[11];
  float* out = (float*)d_out;

  const size_t nodeF = (size_t)kNNodes * EMB;
  float* cur  = (float*)d_ws;                               // 38.4 MB
  float* nbuf = cur + nodeF;                                // 38.4 MB (tmpE alias)
  int2*  edgeS     = (int2*)(nbuf + nodeF);                 // 38.4 MB
  int*   rowPtr    = (int*)(edgeS + kNEdges);               // 600 KB (+1)
  int*   rangeA    = rowPtr + (kNNodes + 1);                // 2.3 KB (+1)
  int*   rangeCnt  = rangeA + (kNRanges + 1);               // 2.3 KB
  unsigned short* cur16 = (unsigned short*)(rangeCnt + kNRanges);  // 19.2 MB
  int2*  tmpE = (int2*)nbuf;                                // binned records
  const size_t neededCsr = (size_t)((char*)cur16 - (char*)d_ws);
  const size_t needed16  = neededCsr + nodeF * sizeof(unsigned short);
  const bool useCsr = ws_size >= neededCsr;
  const bool use16  = useCsr && ws_size >= needed16;

  const dim3 blk(256);
  const int iblocks = (int)((nodeF / 4 + 255) / 256);       // 9375
  const int gblocks = (3 * kBatch * EMB + 255) / 256;       // 12288
  const int rblocks = (kNNodes + 3) / 4;                    // 37500
  const int tblocks = (kNNodes + 255) / 256;                // 586

  init_embed<<<iblocks, blk, 0, stream>>>(user_emb, item_emb, cur, cur16,
                                          use16 ? 1 : 0);

  if (useCsr) {
    // zero rangeA (totals) + rangeCnt (burst frontiers) — contiguous
    hipMemsetAsync(rangeA, 0, (size_t)(2 * kNRanges + 1) * sizeof(int), stream);
    hist_ranges<<<kBinBlocks, blk, 0, stream>>>(rows, rangeA);
    scan_ranges<<<1, 1024, 0, stream>>>(rangeA, rowPtr);
    bin_edges<<<kBinBlocks, blk, 0, stream>>>(rows, cols, vals, rangeA,
                                              rangeCnt, tmpE);
    place_edges<<<kNRanges, blk, 0, stream>>>(tmpE, rangeA, edgeS, rowPtr);
  }

  gather_out<<<gblocks, blk, 0, stream>>>(cur, users, pos, neg, out, 0);

  for (int L = 0; L < kLayers; ++L) {
    if (useCsr) {
      if (use16)
        spmm_csr16<<<rblocks, blk, 0, stream>>>(cur16, rowPtr, edgeS, nbuf);
      else
        spmm_csr<<<rblocks, blk, 0, stream>>>(cur, rowPtr, edgeS, nbuf);
    } else {
      hipMemsetAsync(nbuf, 0, nodeF * sizeof(float), stream);
      const int sblocks = (((kNEdges + kEPW - 1) / kEPW) + 3) / 4;
      spmm_atomic<<<sblocks, blk, 0, stream>>>(cur, rows, cols, vals, nbuf);
    }
    transform_nbr<<<tblocks, blk, 0, stream>>>(
        nbuf, W2s + L * EMB * EMB, b2s + L * EMB);
    transform_self<<<tblocks, blk, 0, stream>>>(
        cur, nbuf, W1s + L * EMB * EMB, b1s + L * EMB,
        b2s + L * EMB, W2s + L * EMB * EMB);
    if (use16 && L + 1 < kLayers)
      refresh16<<<iblocks, blk, 0, stream>>>(cur, cur16);
    gather_out<<<gblocks, blk, 0, stream>>>(cur, users, pos, neg, out, L + 1);
  }
}

// Round 6
// 1283.339 us; speedup vs baseline: 2.3005x; 1.0225x over previous
//
#include <hip/hip_runtime.h>

// NGCF forward on gfx950 — round 12: spmm gather locality + binning occupancy.
// R11 post-mortem: spmm_csr16 FETCH=525MB (vs 57.6 ideal) — each cur16 row
// re-fetched ~32x in random col order, L2 hit 15%. Fix: place_edges now
// orders each row's edges by col-BUCKET (8192 nodes = 1MB of cur16/bucket);
// all waves run the identical iteration sequence, so co-resident waves sweep
// buckets in near-lockstep -> instantaneous working set ~few MB -> L2 hits.
// bin_edges/hist_ranges were 11% occupancy (293 blocks x 256 thr): widen to
// 1024 threads (same blocks, 4x waves).

#define EMB 64

constexpr int kNUsers = 100000;
constexpr int kNItems = 50000;
constexpr int kNNodes = 150000;
constexpr int kNEdges = 4800000;
constexpr int kBatch  = 16384;
constexpr int kLayers = 3;
constexpr int kRngShift = 8;                     // 256 rows per range
constexpr int kNRanges  = (kNNodes + 255) >> 8;  // 586
constexpr int kEdgesPerBin = 16384;              // edges per bin block
constexpr int kBinBlocks = (kNEdges + kEdgesPerBin - 1) / kEdgesPerBin; // 293
constexpr int kBktShift = 13;                    // 8192 nodes per col-bucket
constexpr int kNBkt     = (kNNodes + 8191) >> 13;   // 19
constexpr int kEPW    = 16;                      // fallback only

__device__ __forceinline__ float f4c(const float4& v, int i) {
  return ((const float*)&v)[i];
}
__device__ __forceinline__ float4 f4fma(float s, float4 w, float4 a) {
  a.x = fmaf(s, w.x, a.x);
  a.y = fmaf(s, w.y, a.y);
  a.z = fmaf(s, w.z, a.z);
  a.w = fmaf(s, w.w, a.w);
  return a;
}
__device__ __forceinline__ float4 f4add(float4 a, float4 b) {
  a.x += b.x; a.y += b.y; a.z += b.z; a.w += b.w;
  return a;
}
__device__ __forceinline__ float lrelu(float x) { return x > 0.f ? x : 0.2f * x; }
__device__ __forceinline__ unsigned short f2bf(float f) {   // RNE
  unsigned int u = __float_as_uint(f);
  u = (u + 0x7fffu + ((u >> 16) & 1u)) >> 16;
  return (unsigned short)u;
}
__device__ __forceinline__ float bf2f(unsigned short h) {
  return __uint_as_float(((unsigned int)h) << 16);
}

#define F16(M) M(0) M(1) M(2) M(3) M(4) M(5) M(6) M(7) \
               M(8) M(9) M(10) M(11) M(12) M(13) M(14) M(15)

// ---------------------------------------------------------------------------
// init: cur = concat(user_emb, item_emb); cur16 = bf16(cur).
// ---------------------------------------------------------------------------
__global__ __launch_bounds__(256) void init_embed(
    const float* __restrict__ user_emb, const float* __restrict__ item_emb,
    float* __restrict__ cur, unsigned short* __restrict__ cur16, int with16)
{
  const size_t userF = (size_t)kNUsers * EMB;
  const size_t allF4 = (size_t)kNNodes * EMB / 4;
  const size_t i = (size_t)blockIdx.x * 256 + threadIdx.x;
  if (i >= allF4) return;
  const size_t f = i * 4;
  const float4 v = (f < userF) ? ((const float4*)user_emb)[i]
                               : ((const float4*)(item_emb))[(f - userF) / 4];
  ((float4*)cur)[i] = v;
  if (with16) {
    ushort4 h;
    h.x = f2bf(v.x); h.y = f2bf(v.y); h.z = f2bf(v.z); h.w = f2bf(v.w);
    ((ushort4*)cur16)[i] = h;
  }
}

// Streaming bf16 shadow refresh: cur16 = bf16(cur).
__global__ __launch_bounds__(256) void refresh16(
    const float* __restrict__ cur, unsigned short* __restrict__ cur16)
{
  const size_t allF4 = (size_t)kNNodes * EMB / 4;
  const size_t i = (size_t)blockIdx.x * 256 + threadIdx.x;
  if (i >= allF4) return;
  const float4 v = ((const float4*)cur)[i];
  ushort4 h;
  h.x = f2bf(v.x); h.y = f2bf(v.y); h.z = f2bf(v.z); h.w = f2bf(v.w);
  ((ushort4*)cur16)[i] = h;
}

// ---------------------------------------------------------------------------
// CSR build: range histogram -> range scan -> burst binning -> local place.
// ---------------------------------------------------------------------------

// Per-block LDS histogram over 586 ranges; one global atomic per (block,range).
__global__ __launch_bounds__(1024) void hist_ranges(
    const int* __restrict__ rows, int* __restrict__ rangeA)
{
  __shared__ int cnt[kNRanges];
  const int tid = threadIdx.x;
  const int e0  = blockIdx.x * kEdgesPerBin;
  int e1 = e0 + kEdgesPerBin;
  if (e1 > kNEdges) e1 = kNEdges;
  for (int b = tid; b < kNRanges; b += 1024) cnt[b] = 0;
  __syncthreads();
  for (int e = e0 + tid; e < e1; e += 1024)
    atomicAdd(&cnt[rows[e] >> kRngShift], 1);
  __syncthreads();
  for (int b = tid; b < kNRanges; b += 1024)
    if (cnt[b] > 0) atomicAdd(&rangeA[b], cnt[b]);
}

// Exclusive scan of the 586 range totals, in place (1 block).
__global__ __launch_bounds__(1024) void scan_ranges(
    int* __restrict__ rangeA, int* __restrict__ rowPtr)
{
  __shared__ int wsum[16];
  const int tid  = threadIdx.x;
  const int lane = tid & 63;
  const int wid  = tid >> 6;
  const int cnt  = (tid < kNRanges) ? rangeA[tid] : 0;
  int v = cnt;
#pragma unroll
  for (int off = 1; off < 64; off <<= 1) {
    const int n = __shfl_up(v, off, 64);
    if (lane >= off) v += n;
  }
  if (lane == 63) wsum[wid] = v;
  __syncthreads();
  if (tid == 0) {
    int s = 0;
#pragma unroll
    for (int w = 0; w < 16; ++w) { const int t = wsum[w]; wsum[w] = s; s += t; }
  }
  __syncthreads();
  if (tid < kNRanges) rangeA[tid] = wsum[wid] + v - cnt;
  if (tid == 0) {
    rangeA[kNRanges]  = kNEdges;
    rowPtr[kNNodes]   = kNEdges;
  }
}

// Bin edges into 586 row-ranges. Per block: LDS histogram, ONE global atomic
// per (block,range) reserving a contiguous burst off rangeStart, then scatter
// into the exclusively-owned burst. Record: col | localRow<<18.
__global__ __launch_bounds__(1024) void bin_edges(
    const int* __restrict__ rows, const int* __restrict__ cols,
    const float* __restrict__ vals, const int* __restrict__ rangeA,
    int* __restrict__ rangeCnt, int2* __restrict__ tmpE)
{
  __shared__ int cnt[kNRanges];
  __shared__ int base[kNRanges];
  const int tid = threadIdx.x;
  const int e0  = blockIdx.x * kEdgesPerBin;
  int e1 = e0 + kEdgesPerBin;
  if (e1 > kNEdges) e1 = kNEdges;

  for (int b = tid; b < kNRanges; b += 1024) cnt[b] = 0;
  __syncthreads();
  for (int e = e0 + tid; e < e1; e += 1024)
    atomicAdd(&cnt[rows[e] >> kRngShift], 1);
  __syncthreads();
  for (int b = tid; b < kNRanges; b += 1024) {
    const int c = cnt[b];
    base[b] = (c > 0) ? (rangeA[b] + atomicAdd(&rangeCnt[b], c)) : 0;
    cnt[b] = 0;
  }
  __syncthreads();
  for (int e = e0 + tid; e < e1; e += 1024) {
    const int r = rows[e];
    const int b = r >> kRngShift;
    const int rank = atomicAdd(&cnt[b], 1);
    tmpE[base[b] + rank] =
        make_int2(cols[e] | ((r & 255) << 18), __float_as_int(vals[e]));
  }
}

// One WG per range: derive per-row CSR locally AND order each row's edges by
// col-bucket (19 buckets x 8192 nodes). Per-(row,bucket) LDS counts, per-row
// block scan for rowPtr, per-row serial bucket scan, then place.
__global__ __launch_bounds__(256) void place_edges(
    const int2* __restrict__ tmpE, const int* __restrict__ rangeA,
    int2* __restrict__ edgeS, int* __restrict__ rowPtr)
{
  __shared__ int bcnt[256][kNBkt];
  __shared__ int ws[4];
  const int b    = blockIdx.x;
  const int r0   = b << kRngShift;
  const int tid  = threadIdx.x;
  const int lane = tid & 63;
  const int wid  = tid >> 6;
  const int start = rangeA[b];
  const int end   = rangeA[b + 1];

#pragma unroll
  for (int k = 0; k < kNBkt; ++k) bcnt[tid][k] = 0;
  __syncthreads();
  for (int e = start + tid; e < end; e += 256) {
    const int cv = tmpE[e].x;
    atomicAdd(&bcnt[(cv >> 18) & 255][(cv & 0x3FFFF) >> kBktShift], 1);
  }
  __syncthreads();

  int c = 0;                       // own row's total edge count
#pragma unroll
  for (int k = 0; k < kNBkt; ++k) c += bcnt[tid][k];
  int v = c;
#pragma unroll
  for (int off = 1; off < 64; off <<= 1) {
    const int n = __shfl_up(v, off, 64);
    if (lane >= off) v += n;
  }
  if (lane == 63) ws[wid] = v;
  __syncthreads();
  int wadd = 0;
#pragma unroll
  for (int w = 0; w < 4; ++w) if (w < wid) wadd += ws[w];
  const int rbase = start + v - c + wadd;   // absolute start of this row
  if (r0 + tid < kNNodes) rowPtr[r0 + tid] = rbase;
  // per-row bucket exclusive scan -> bcnt becomes absolute slot frontiers
  int off = rbase;
#pragma unroll
  for (int k = 0; k < kNBkt; ++k) {
    const int t = bcnt[tid][k];
    bcnt[tid][k] = off;
    off += t;
  }
  __syncthreads();

  for (int e = start + tid; e < end; e += 256) {
    const int2 cv = tmpE[e];
    const int rl  = (cv.x >> 18) & 255;
    const int col = cv.x & 0x3FFFF;
    const int slot = atomicAdd(&bcnt[rl][col >> kBktShift], 1);
    edgeS[slot] = make_int2(col, cv.y);
  }
}

// ---------------------------------------------------------------------------
// CSR SpMM, bf16 gather: one wave per row, lane = dim; 128 B/edge gather.
// Edges are col-bucket-ordered -> co-resident waves sweep cur16 in lockstep.
// ---------------------------------------------------------------------------
__global__ __launch_bounds__(256) void spmm_csr16(
    const unsigned short* __restrict__ cur16, const int* __restrict__ rowPtr,
    const int2* __restrict__ edgeS, float* __restrict__ nbuf)
{
  const int lane = threadIdx.x & 63;
  const int r = (blockIdx.x << 2) | (threadIdx.x >> 6);
  if (r >= kNNodes) return;
  const int start = __builtin_amdgcn_readfirstlane(rowPtr[r]);
  const int end   = __builtin_amdgcn_readfirstlane(rowPtr[r + 1]);
  float a0 = 0.f, a1 = 0.f, a2 = 0.f, a3 = 0.f;
  int e = start;
  for (; e + 4 <= end; e += 4) {
    const int2 cv0 = edgeS[e];
    const int2 cv1 = edgeS[e + 1];
    const int2 cv2 = edgeS[e + 2];
    const int2 cv3 = edgeS[e + 3];
    const unsigned short u0 = cur16[(size_t)cv0.x * EMB + lane];
    const unsigned short u1 = cur16[(size_t)cv1.x * EMB + lane];
    const unsigned short u2 = cur16[(size_t)cv2.x * EMB + lane];
    const unsigned short u3 = cur16[(size_t)cv3.x * EMB + lane];
    a0 = fmaf(__int_as_float(cv0.y), bf2f(u0), a0);
    a1 = fmaf(__int_as_float(cv1.y), bf2f(u1), a1);
    a2 = fmaf(__int_as_float(cv2.y), bf2f(u2), a2);
    a3 = fmaf(__int_as_float(cv3.y), bf2f(u3), a3);
  }
  for (; e < end; ++e) {
    const int2 cv = edgeS[e];
    a0 = fmaf(__int_as_float(cv.y), bf2f(cur16[(size_t)cv.x * EMB + lane]), a0);
  }
  nbuf[(size_t)r * EMB + lane] = (a0 + a1) + (a2 + a3);
}

// fp32-gather variant (fallback when ws can't hold cur16)
__global__ __launch_bounds__(256) void spmm_csr(
    const float* __restrict__ cur, const int* __restrict__ rowPtr,
    const int2* __restrict__ edgeS, float* __restrict__ nbuf)
{
  const int lane = threadIdx.x & 63;
  const int r = (blockIdx.x << 2) | (threadIdx.x >> 6);
  if (r >= kNNodes) return;
  const int start = __builtin_amdgcn_readfirstlane(rowPtr[r]);
  const int end   = __builtin_amdgcn_readfirstlane(rowPtr[r + 1]);
  float a0 = 0.f, a1 = 0.f, a2 = 0.f, a3 = 0.f;
  int e = start;
  for (; e + 4 <= end; e += 4) {
    const int2 cv0 = edgeS[e];
    const int2 cv1 = edgeS[e + 1];
    const int2 cv2 = edgeS[e + 2];
    const int2 cv3 = edgeS[e + 3];
    a0 = fmaf(__int_as_float(cv0.y), cur[(size_t)cv0.x * EMB + lane], a0);
    a1 = fmaf(__int_as_float(cv1.y), cur[(size_t)cv1.x * EMB + lane], a1);
    a2 = fmaf(__int_as_float(cv2.y), cur[(size_t)cv2.x * EMB + lane], a2);
    a3 = fmaf(__int_as_float(cv3.y), cur[(size_t)cv3.x * EMB + lane], a3);
  }
  for (; e < end; ++e) {
    const int2 cv = edgeS[e];
    a0 = fmaf(__int_as_float(cv.y), cur[(size_t)cv.x * EMB + lane], a0);
  }
  nbuf[(size_t)r * EMB + lane] = (a0 + a1) + (a2 + a3);
}

__global__ __launch_bounds__(256) void spmm_atomic(
    const float* __restrict__ cur, const int* __restrict__ rows,
    const int* __restrict__ cols, const float* __restrict__ vals,
    float* __restrict__ nbuf)
{
  const int lane = threadIdx.x & 63;
  int wv = (blockIdx.x << 2) | (threadIdx.x >> 6);
  wv = __builtin_amdgcn_readfirstlane(wv);
  int e0 = wv * kEPW;
  int e1 = e0 + kEPW;
  if (e1 > kNEdges) e1 = kNEdges;
  for (int e = e0; e < e1; ++e) {
    atomicAdd(nbuf + (size_t)rows[e] * EMB + lane,
              vals[e] * cur[(size_t)cols[e] * EMB + lane]);
  }
}

// ---------------------------------------------------------------------------
// Transform pass 1: t = n@W2 + b2, in place over nbuf. Named-register accs.
// ---------------------------------------------------------------------------
__global__ __launch_bounds__(256) void transform_nbr(
    float* __restrict__ nbuf, const float* __restrict__ W2,
    const float* __restrict__ b2)
{
  const int node = blockIdx.x * 256 + threadIdx.x;
  if (node >= kNNodes) return;
  const float4* __restrict__ nr  = (const float4*)(nbuf + (size_t)node * EMB);
  const float4* __restrict__ b2v = (const float4*)b2;
#define DECL(j) float4 a##j = b2v[j];
  F16(DECL)
#undef DECL
#pragma unroll 4
  for (int k4 = 0; k4 < 16; ++k4) {
    const float4 nv = nr[k4];
#pragma unroll
    for (int kk = 0; kk < 4; ++kk) {
      const float ns = f4c(nv, kk);
      const float4* __restrict__ w2r = (const float4*)(W2 + (4 * k4 + kk) * EMB);
#define STEP(j) a##j = f4fma(ns, w2r[j], a##j);
      F16(STEP)
#undef STEP
    }
  }
  float4* __restrict__ outp = (float4*)(nbuf + (size_t)node * EMB);
#define STORE(j) outp[j] = a##j;
  F16(STORE)
#undef STORE
}

// ---------------------------------------------------------------------------
// Transform pass 2: cur = lrelu(x@W1 + b1 + b2 + (t*x)@W2 + t), t from nbuf.
// ---------------------------------------------------------------------------
__global__ __launch_bounds__(256) void transform_self(
    float* __restrict__ cur, const float* __restrict__ nbuf,
    const float* __restrict__ W1, const float* __restrict__ b1,
    const float* __restrict__ b2, const float* __restrict__ W2)
{
  const int node = blockIdx.x * 256 + threadIdx.x;
  if (node >= kNNodes) return;
  const float4* __restrict__ xr  = (const float4*)(cur  + (size_t)node * EMB);
  const float4* __restrict__ tr  = (const float4*)(nbuf + (size_t)node * EMB);
  const float4* __restrict__ b1v = (const float4*)b1;
  const float4* __restrict__ b2v = (const float4*)b2;
#define DECL(j) float4 a##j = f4add(b1v[j], b2v[j]);
  F16(DECL)
#undef DECL
#pragma unroll 2
  for (int k4 = 0; k4 < 16; ++k4) {
    const float4 xv = xr[k4];
    const float4 tv = tr[k4];
#pragma unroll
    for (int kk = 0; kk < 4; ++kk) {
      const float xs = f4c(xv, kk);
      const float ms = f4c(tv, kk) * xs;
      const int k = 4 * k4 + kk;
      const float4* __restrict__ w1r = (const float4*)(W1 + k * EMB);
      const float4* __restrict__ w2r = (const float4*)(W2 + k * EMB);
#define STEP(j) a##j = f4fma(xs, w1r[j], a##j); a##j = f4fma(ms, w2r[j], a##j);
      F16(STEP)
#undef STEP
    }
  }
  float4* __restrict__ outp = (float4*)(cur + (size_t)node * EMB);
#define STORE(j) { const float4 tj = tr[j]; float4 r;          \
    r.x = lrelu(a##j.x + tj.x); r.y = lrelu(a##j.y + tj.y);    \
    r.z = lrelu(a##j.z + tj.z); r.w = lrelu(a##j.w + tj.w);    \
    outp[j] = r; }
  F16(STORE)
#undef STORE
}

// ---------------------------------------------------------------------------
__global__ __launch_bounds__(256) void gather_out(
    const float* __restrict__ cur, const int* __restrict__ users,
    const int* __restrict__ pos, const int* __restrict__ neg,
    float* __restrict__ out, int layer)
{
  const int t    = blockIdx.x * 256 + threadIdx.x;
  const int lane = t & 63;
  const int rid  = t >> 6;
  if (rid >= 3 * kBatch) return;
  const int seg = rid / kBatch;
  const int b   = rid - seg * kBatch;
  int idx;
  if (seg == 0)      idx = users[b];
  else if (seg == 1) idx = pos[b] + kNUsers;
  else               idx = neg[b] + kNUsers;
  out[(size_t)rid * 256 + layer * EMB + lane] = cur[(size_t)idx * EMB + lane];
}

// ---------------------------------------------------------------------------
extern "C" void kernel_launch(void* const* d_in, const int* in_sizes, int n_in,
                              void* d_out, int out_size, void* d_ws, size_t ws_size,
                              hipStream_t stream) {
  const int*   users    = (const int*)d_in[0];
  const int*   pos      = (const int*)d_in[1];
  const int*   neg      = (const int*)d_in[2];
  const int*   rows     = (const int*)d_in[3];
  const int*   cols     = (const int*)d_in[4];
  const float* vals     = (const float*)d_in[5];
  const float* user_emb = (const float*)d_in[6];
  const float* item_emb = (const float*)d_in[7];
  const float* W1s      = (const float*)d_in[8];
  const float* b1s      = (const float*)d_in[9];
  const float* W2s      = (const float*)d_in[10];
  const float* b2s      = (const float*)d_in[11];
  float* out = (float*)d_out;

  const size_t nodeF = (size_t)kNNodes * EMB;
  float* cur  = (float*)d_ws;                               // 38.4 MB
  float* nbuf = cur + nodeF;                                // 38.4 MB (tmpE alias)
  int2*  edgeS     = (int2*)(nbuf + nodeF);                 // 38.4 MB
  int*   rowPtr    = (int*)(edgeS + kNEdges);               // 600 KB (+1)
  int*   rangeA    = rowPtr + (kNNodes + 1);                // 2.3 KB (+1)
  int*   rangeCnt  = rangeA + (kNRanges + 1);               // 2.3 KB
  unsigned short* cur16 = (unsigned short*)(rangeCnt + kNRanges);  // 19.2 MB
  int2*  tmpE = (int2*)nbuf;                                // binned records
  const size_t neededCsr = (size_t)((char*)cur16 - (char*)d_ws);
  const size_t needed16  = neededCsr + nodeF * sizeof(unsigned short);
  const bool useCsr = ws_size >= neededCsr;
  const bool use16  = useCsr && ws_size >= needed16;

  const dim3 blk(256);
  const int iblocks = (int)((nodeF / 4 + 255) / 256);       // 9375
  const int gblocks = (3 * kBatch * EMB + 255) / 256;       // 12288
  const int rblocks = (kNNodes + 3) / 4;                    // 37500
  const int tblocks = (kNNodes + 255) / 256;                // 586

  init_embed<<<iblocks, blk, 0, stream>>>(user_emb, item_emb, cur, cur16,
                                          use16 ? 1 : 0);

  if (useCsr) {
    // zero rangeA (totals) + rangeCnt (burst frontiers) — contiguous
    hipMemsetAsync(rangeA, 0, (size_t)(2 * kNRanges + 1) * sizeof(int), stream);
    hist_ranges<<<kBinBlocks, dim3(1024), 0, stream>>>(rows, rangeA);
    scan_ranges<<<1, 1024, 0, stream>>>(rangeA, rowPtr);
    bin_edges<<<kBinBlocks, dim3(1024), 0, stream>>>(rows, cols, vals, rangeA,
                                                     rangeCnt, tmpE);
    place_edges<<<kNRanges, blk, 0, stream>>>(tmpE, rangeA, edgeS, rowPtr);
  }

  gather_out<<<gblocks, blk, 0, stream>>>(cur, users, pos, neg, out, 0);

  for (int L = 0; L < kLayers; ++L) {
    if (useCsr) {
      if (use16)
        spmm_csr16<<<rblocks, blk, 0, stream>>>(cur16, rowPtr, edgeS, nbuf);
      else
        spmm_csr<<<rblocks, blk, 0, stream>>>(cur, rowPtr, edgeS, nbuf);
    } else {
      hipMemsetAsync(nbuf, 0, nodeF * sizeof(float), stream);
      const int sblocks = (((kNEdges + kEPW - 1) / kEPW) + 3) / 4;
      spmm_atomic<<<sblocks, blk, 0, stream>>>(cur, rows, cols, vals, nbuf);
    }
    transform_nbr<<<tblocks, blk, 0, stream>>>(
        nbuf, W2s + L * EMB * EMB, b2s + L * EMB);
    transform_self<<<tblocks, blk, 0, stream>>>(
        cur, nbuf, W1s + L * EMB * EMB, b1s + L * EMB,
        b2s + L * EMB, W2s + L * EMB * EMB);
    if (use16 && L + 1 < kLayers)
      refresh16<<<iblocks, blk, 0, stream>>>(cur, cur16);
    gather_out<<<gblocks, blk, 0, stream>>>(cur, users, pos, neg, out, L + 1);
  }
}